// Round 3
// baseline (240467.700 us; speedup 1.0000x reference)
//
#include <hip/hip_runtime.h>

#define NB 256    // batch
#define NT 512    // T == MAXLEN
#define NI 512    // INPUTS == M
#define NH 512    // HIDDEN
#define NG 1536   // 3*H
#define NBLK 512  // persistent grid

typedef __attribute__((ext_vector_type(8))) short bf16x8;
typedef __attribute__((ext_vector_type(4))) float f32x4;

#define MFMA(a, b, c) __builtin_amdgcn_mfma_f32_16x16x32_bf16((a), (b), (c), 0, 0, 0)

__device__ __forceinline__ unsigned short f2bf(float f) {
  unsigned int u = __float_as_uint(f);
  u = u + 0x7FFFu + ((u >> 16) & 1u);
  return (unsigned short)(u >> 16);
}
__device__ __forceinline__ float bflo(unsigned int p) { return __uint_as_float(p << 16); }
__device__ __forceinline__ float bfhi(unsigned int p) { return __uint_as_float(p & 0xffff0000u); }
__device__ __forceinline__ float sigm(float x) { return 1.f / (1.f + __expf(-x)); }

// ---------------- generic f32 -> bf16 cast ----------------
__global__ __launch_bounds__(256) void cast_f32_bf16(const float* __restrict__ s,
                                                     unsigned short* __restrict__ d, int n) {
  int i = blockIdx.x * 256 + threadIdx.x;
  int stride = gridDim.x * 256;
  for (; i < n; i += stride) d[i] = f2bf(s[i]);
}

// ---------------- Zt = (bf16 X) @ Wc2^T, in place over Xc ----------------
// flat rows = b*512 + m (131072 rows of 512). Each block owns 32 rows: stages them
// to LDS, then computes out rows = same rows (in-place safe: no cross-block row reads).
__global__ __launch_bounds__(256) void zt_inplace(unsigned short* __restrict__ XZ,
                                                  const unsigned short* __restrict__ Wc) {
  __shared__ unsigned short As[32][552];   // padded: stride 1104B, 16B-aligned, ~2-way banks
  const int tid = threadIdx.x;
  const int row0 = blockIdx.x * 32;
  const uint4* src = (const uint4*)(XZ + (size_t)row0 * 512);   // 32 rows contiguous = 2048 uint4
#pragma unroll
  for (int it = 0; it < 8; ++it) {
    int e8 = tid + it * 256;
    uint4 v = src[e8];
    *(uint4*)&As[e8 >> 6][(e8 & 63) * 8] = v;
  }
  __syncthreads();
  const int lane = tid & 63, w = tid >> 6;
  const int al = lane & 15, kg = lane >> 4;
  const int rbase = (w & 1) * 16;
  const int cbase = (w >> 1) * 256;
  for (int cc = 0; cc < 16; ++cc) {
    int col0 = cbase + cc * 16;
    f32x4 acc = {0.f, 0.f, 0.f, 0.f};
    const unsigned short* Bp = Wc + (size_t)(col0 + al) * 1024 + 512;
    for (int k = 0; k < 512; k += 32) {
      bf16x8 av = *(const bf16x8*)&As[rbase + al][k + kg * 8];
      bf16x8 bv = *(const bf16x8*)(Bp + k + kg * 8);
      acc = MFMA(av, bv, acc);
    }
#pragma unroll
    for (int r = 0; r < 4; ++r) {
      int row = row0 + rbase + kg * 4 + r;
      XZ[(size_t)row * 512 + col0 + al] = f2bf(acc[r]);
    }
  }
}

// ---------------- init: Xt slot0 = x[:, :, 0], h = 0, barrier = 0 ----------------
__global__ __launch_bounds__(256) void init_kernel(const float* __restrict__ x,
                                                   unsigned short* __restrict__ Xt,
                                                   unsigned short* __restrict__ Hbf,
                                                   float* __restrict__ hbuf,
                                                   unsigned* __restrict__ bar) {
  int idx = blockIdx.x * 256 + threadIdx.x;
  if (blockIdx.x == 0 && threadIdx.x < 2) bar[threadIdx.x] = 0u;
  if (idx < NB * NI) {
    int b = idx >> 9, i = idx & 511;
    Xt[idx] = f2bf(x[((size_t)b * 512 + i) * 512]);
    Hbf[idx] = 0;
    hbuf[idx] = 0.f;
  }
}

struct KParams {
  const unsigned short* XZ;   // Zt [b][m][h] bf16 (in old Xc slot)
  const unsigned short* Wa;   // [512][1024]
  const unsigned short* Whh;  // [1536][512]
  const unsigned short* Wc;   // [512][1024]
  const unsigned short* Wih;  // [1536][512]
  const unsigned short* Wout; // [512][512]
  unsigned short* Xt;         // [2][256][512] bf16 x_t double buffer
  unsigned short* Hbf;        // [256][512] bf16 h
  unsigned short* Gbf;        // [256][512] bf16 g
  float* logits;              // [256][512]
  float* gh;                  // [256][1536]
  float* gx;                  // [256][512]  (Wc1 @ x_t + b_comb)
  float* hbuf;                // [256][512] f32 h carry
  const float* x;
  const float* b_attn;
  const float* b_hh;
  const float* b_ih;
  const float* b_comb;
  const float* b_out;
  float* out;
  unsigned* bar;
};

// sense-reversing grid barrier: bar[0]=count, bar[1]=generation
__device__ __forceinline__ void gbar(unsigned* bar) {
  __syncthreads();
  if (threadIdx.x == 0) {
    unsigned g = __hip_atomic_load(&bar[1], __ATOMIC_RELAXED, __HIP_MEMORY_SCOPE_AGENT);
    unsigned old = __hip_atomic_fetch_add(&bar[0], 1u, __ATOMIC_ACQ_REL, __HIP_MEMORY_SCOPE_AGENT);
    if (old == NBLK - 1) {
      __hip_atomic_store(&bar[0], 0u, __ATOMIC_RELAXED, __HIP_MEMORY_SCOPE_AGENT);
      __hip_atomic_store(&bar[1], g + 1u, __ATOMIC_RELEASE, __HIP_MEMORY_SCOPE_AGENT);
    } else {
      while (__hip_atomic_load(&bar[1], __ATOMIC_ACQUIRE, __HIP_MEMORY_SCOPE_AGENT) == g)
        __builtin_amdgcn_s_sleep(1);
    }
  }
  __syncthreads();
}

__global__ __launch_bounds__(256, 2) void persistent_kernel(KParams P) {
  __shared__ float aw[512];
  __shared__ float4 part[4][64];
  __shared__ float red[8];
  const int bid = blockIdx.x, tid = threadIdx.x;
  const int lane = tid & 63, w = tid >> 6;
  const int al = lane & 15, kg = lane >> 4;

  for (int t = 0; t < NT; ++t) {
    const int p = t & 1, np = p ^ 1;
    // ================= P1: logits | gh | gx | gather x_{t+1} =================
    if (bid < 64) {
      // logits = [xt|h] @ Wa^T + b_attn : tile 64r x 32c
      int rt = bid >> 4, ct = bid & 15;
      int row0 = rt * 64 + w * 16, col0 = ct * 32;
      const unsigned short* Ax = P.Xt + (size_t)p * (NB * NI) + (size_t)(row0 + al) * NI;
      const unsigned short* Ah = P.Hbf + (size_t)(row0 + al) * NH;
      const unsigned short* B0 = P.Wa + (size_t)(col0 + al) * 1024;
      const unsigned short* B1 = P.Wa + (size_t)(col0 + 16 + al) * 1024;
      f32x4 a0 = {0.f, 0.f, 0.f, 0.f}, a1 = {0.f, 0.f, 0.f, 0.f};
      for (int k = 0; k < 512; k += 32) {
        bf16x8 av = *(const bf16x8*)(Ax + k + kg * 8);
        a0 = MFMA(av, *(const bf16x8*)(B0 + k + kg * 8), a0);
        a1 = MFMA(av, *(const bf16x8*)(B1 + k + kg * 8), a1);
      }
      for (int k = 0; k < 512; k += 32) {
        bf16x8 av = *(const bf16x8*)(Ah + k + kg * 8);
        a0 = MFMA(av, *(const bf16x8*)(B0 + 512 + k + kg * 8), a0);
        a1 = MFMA(av, *(const bf16x8*)(B1 + 512 + k + kg * 8), a1);
      }
#pragma unroll
      for (int r = 0; r < 4; ++r) {
        int row = row0 + kg * 4 + r;
        P.logits[row * NI + col0 + al] = a0[r] + P.b_attn[col0 + al];
        P.logits[row * NI + col0 + 16 + al] = a1[r] + P.b_attn[col0 + 16 + al];
      }
    } else if (bid < 256) {
      // gh = h @ Whh^T + b_hh : tile 64r x 32c of 1536
      int b2 = bid - 64;
      int rt = b2 / 48, ct = b2 % 48;
      int row0 = rt * 64 + w * 16, col0 = ct * 32;
      const unsigned short* Ah = P.Hbf + (size_t)(row0 + al) * NH;
      const unsigned short* B0 = P.Whh + (size_t)(col0 + al) * 512;
      const unsigned short* B1 = P.Whh + (size_t)(col0 + 16 + al) * 512;
      f32x4 a0 = {0.f, 0.f, 0.f, 0.f}, a1 = {0.f, 0.f, 0.f, 0.f};
      for (int k = 0; k < 512; k += 32) {
        bf16x8 av = *(const bf16x8*)(Ah + k + kg * 8);
        a0 = MFMA(av, *(const bf16x8*)(B0 + k + kg * 8), a0);
        a1 = MFMA(av, *(const bf16x8*)(B1 + k + kg * 8), a1);
      }
      const float* bh = P.b_hh;
#pragma unroll
      for (int r = 0; r < 4; ++r) {
        int row = row0 + kg * 4 + r;
        P.gh[row * NG + col0 + al] = a0[r] + bh[col0 + al];
        P.gh[row * NG + col0 + 16 + al] = a1[r] + bh[col0 + 16 + al];
      }
    } else if (bid < 320) {
      // gx = xt @ Wc1^T + b_comb : tile 64r x 32c
      int b3 = bid - 256;
      int rt = b3 >> 4, ct = b3 & 15;
      int row0 = rt * 64 + w * 16, col0 = ct * 32;
      const unsigned short* Ax = P.Xt + (size_t)p * (NB * NI) + (size_t)(row0 + al) * NI;
      const unsigned short* B0 = P.Wc + (size_t)(col0 + al) * 1024;
      const unsigned short* B1 = P.Wc + (size_t)(col0 + 16 + al) * 1024;
      f32x4 a0 = {0.f, 0.f, 0.f, 0.f}, a1 = {0.f, 0.f, 0.f, 0.f};
      for (int k = 0; k < 512; k += 32) {
        bf16x8 av = *(const bf16x8*)(Ax + k + kg * 8);
        a0 = MFMA(av, *(const bf16x8*)(B0 + k + kg * 8), a0);
        a1 = MFMA(av, *(const bf16x8*)(B1 + k + kg * 8), a1);
      }
#pragma unroll
      for (int r = 0; r < 4; ++r) {
        int row = row0 + kg * 4 + r;
        P.gx[row * NH + col0 + al] = a0[r] + P.b_comb[col0 + al];
        P.gx[row * NH + col0 + 16 + al] = a1[r] + P.b_comb[col0 + 16 + al];
      }
    } else {
      // gather x_{t+1} column into Xt[np]
      if (t < NT - 1) {
        for (int e = (bid - 320) * 256 + tid; e < NB * NI; e += 192 * 256) {
          int b = e >> 9, i = e & 511;
          P.Xt[(size_t)np * (NB * NI) + e] = f2bf(P.x[((size_t)b * 512 + i) * 512 + t + 1]);
        }
      }
    }
    gbar(P.bar);

    // ================= P2: softmax + Zt-stream -> g =================
    {
      const int b = bid >> 1, half = bid & 1;
      float2 lv = ((const float2*)(P.logits + (size_t)b * NI))[tid];
      float mx = fmaxf(lv.x, lv.y);
#pragma unroll
      for (int off = 32; off >= 1; off >>= 1) mx = fmaxf(mx, __shfl_xor(mx, off));
      if (lane == 0) red[w] = mx;
      __syncthreads();
      mx = fmaxf(fmaxf(red[0], red[1]), fmaxf(red[2], red[3]));
      float e0 = __expf(lv.x - mx), e1 = __expf(lv.y - mx);
      float sm = e0 + e1;
#pragma unroll
      for (int off = 32; off >= 1; off >>= 1) sm += __shfl_xor(sm, off);
      if (lane == 0) red[4 + w] = sm;
      __syncthreads();
      sm = (red[4] + red[5]) + (red[6] + red[7]);
      float inv = 1.f / sm;
      aw[2 * tid] = e0 * inv;
      aw[2 * tid + 1] = e1 * inv;
      __syncthreads();

      // stream Zt[b][m][h-quad]: wave w handles m === w (mod 4); lane owns h-quad
      const uint2* X2 = (const uint2*)P.XZ + ((size_t)b << 16) + half * 64 + lane;
      float4 c = {0.f, 0.f, 0.f, 0.f};
      for (int mi = 0; mi < 128; mi += 16) {
        uint2 px[16];
        float av_[16];
#pragma unroll
        for (int u = 0; u < 16; ++u) px[u] = X2[(size_t)((mi + u) * 4 + w) * 128];
#pragma unroll
        for (int u = 0; u < 16; ++u) av_[u] = aw[(mi + u) * 4 + w];
#pragma unroll
        for (int u = 0; u < 16; ++u) {
          c.x = fmaf(av_[u], bflo(px[u].x), c.x);
          c.y = fmaf(av_[u], bfhi(px[u].x), c.y);
          c.z = fmaf(av_[u], bflo(px[u].y), c.z);
          c.w = fmaf(av_[u], bfhi(px[u].y), c.w);
        }
      }
      part[w][lane] = c;
      __syncthreads();
      if (w == 0) {
        float4 s0 = part[0][lane], s1 = part[1][lane], s2 = part[2][lane], s3 = part[3][lane];
        int h0 = half * 256 + lane * 4;
        const float4 gxv = *(const float4*)(P.gx + (size_t)b * NH + h0);
        float v0 = fmaxf(gxv.x + ((s0.x + s1.x) + (s2.x + s3.x)), 0.f);
        float v1 = fmaxf(gxv.y + ((s0.y + s1.y) + (s2.y + s3.y)), 0.f);
        float v2 = fmaxf(gxv.z + ((s0.z + s1.z) + (s2.z + s3.z)), 0.f);
        float v3 = fmaxf(gxv.w + ((s0.w + s1.w) + (s2.w + s3.w)), 0.f);
        uint2 o;
        o.x = (unsigned)f2bf(v0) | ((unsigned)f2bf(v1) << 16);
        o.y = (unsigned)f2bf(v2) | ((unsigned)f2bf(v3) << 16);
        *(uint2*)(P.Gbf + (size_t)b * NH + h0) = o;
      }
    }
    gbar(P.bar);

    // ================= P3: GRU gates -> h' =================
    if (bid < 128) {
      int rt = bid >> 4, ct = bid & 15;
      int row0 = rt * 32 + (w & 1) * 16;
      int j0 = ct * 32 + (w >> 1) * 16;
      const unsigned short* Ag = P.Gbf + (size_t)(row0 + al) * NH;
      const unsigned short* Br = P.Wih + (size_t)(j0 + al) * 512;
      const unsigned short* Bz = P.Wih + (size_t)(j0 + 512 + al) * 512;
      const unsigned short* Bn = P.Wih + (size_t)(j0 + 1024 + al) * 512;
      f32x4 ar = {0.f, 0.f, 0.f, 0.f}, az = {0.f, 0.f, 0.f, 0.f}, an = {0.f, 0.f, 0.f, 0.f};
      for (int k = 0; k < 512; k += 32) {
        bf16x8 av = *(const bf16x8*)(Ag + k + kg * 8);
        ar = MFMA(av, *(const bf16x8*)(Br + k + kg * 8), ar);
        az = MFMA(av, *(const bf16x8*)(Bz + k + kg * 8), az);
        an = MFMA(av, *(const bf16x8*)(Bn + k + kg * 8), an);
      }
      int j = j0 + al;
      float bir = P.b_ih[j], biz = P.b_ih[j + 512], bin_ = P.b_ih[j + 1024];
#pragma unroll
      for (int r = 0; r < 4; ++r) {
        int row = row0 + kg * 4 + r;
        const float* ghrow = P.gh + (size_t)row * NG;
        float rg = sigm(ar[r] + bir + ghrow[j]);
        float zg = sigm(az[r] + biz + ghrow[j + 512]);
        float ng = tanhf(an[r] + bin_ + rg * ghrow[j + 1024]);
        float ho = P.hbuf[row * NH + j];
        float hn = (1.f - zg) * ng + zg * ho;
        P.hbuf[row * NH + j] = hn;
        P.Hbf[row * NH + j] = f2bf(hn);
      }
    }
    gbar(P.bar);
  }

  // ================= P5: out = h_T @ Wout^T + b_out =================
  if (bid < 128) {
    int rt = bid >> 4, ct = bid & 15;
    int row0 = rt * 32 + (w & 1) * 16;
    int col0 = ct * 32 + (w >> 1) * 16;
    const unsigned short* Ah = P.Hbf + (size_t)(row0 + al) * NH;
    const unsigned short* B0 = P.Wout + (size_t)(col0 + al) * 512;
    f32x4 acc = {0.f, 0.f, 0.f, 0.f};
    for (int k = 0; k < 512; k += 32) {
      bf16x8 av = *(const bf16x8*)(Ah + k + kg * 8);
      acc = MFMA(av, *(const bf16x8*)(B0 + k + kg * 8), acc);
    }
#pragma unroll
    for (int r = 0; r < 4; ++r) {
      int row = row0 + kg * 4 + r;
      P.out[row * 512 + col0 + al] = acc[r] + P.b_out[col0 + al];
    }
  }
}

extern "C" void kernel_launch(void* const* d_in, const int* in_sizes, int n_in,
                              void* d_out, int out_size, void* d_ws, size_t ws_size,
                              hipStream_t stream) {
  const float* x      = (const float*)d_in[0];
  const float* W_attn = (const float*)d_in[1];
  const float* b_attn = (const float*)d_in[2];
  const float* W_comb = (const float*)d_in[3];
  const float* b_comb = (const float*)d_in[4];
  const float* W_ih   = (const float*)d_in[5];
  const float* W_hh   = (const float*)d_in[6];
  const float* b_ih   = (const float*)d_in[7];
  const float* b_hh   = (const float*)d_in[8];
  const float* W_out  = (const float*)d_in[9];
  const float* b_out  = (const float*)d_in[10];

  char* wp = (char*)d_ws;
  size_t off = 0;
  unsigned short* XZ   = (unsigned short*)(wp + off); off += (size_t)NB * NI * NH * 2;   // 128MB (Xc then Zt)
  unsigned short* Wa   = (unsigned short*)(wp + off); off += (size_t)NI * 1024 * 2;
  unsigned short* Whh  = (unsigned short*)(wp + off); off += (size_t)NG * 512 * 2;
  unsigned short* Wc   = (unsigned short*)(wp + off); off += (size_t)NH * 1024 * 2;
  unsigned short* Wih  = (unsigned short*)(wp + off); off += (size_t)NG * 512 * 2;
  unsigned short* Wout = (unsigned short*)(wp + off); off += (size_t)512 * 512 * 2;
  unsigned short* Xt   = (unsigned short*)(wp + off); off += (size_t)2 * NB * NI * 2;
  unsigned short* Hbf  = (unsigned short*)(wp + off); off += (size_t)NB * NH * 2;
  unsigned short* Gbf  = (unsigned short*)(wp + off); off += (size_t)NB * NH * 2;
  float* logits        = (float*)(wp + off); off += (size_t)NB * NI * 4;
  float* gh            = (float*)(wp + off); off += (size_t)NB * NG * 4;
  float* gx            = (float*)(wp + off); off += (size_t)NB * NH * 4;
  float* hbuf          = (float*)(wp + off); off += (size_t)NB * NH * 4;
  unsigned* bar        = (unsigned*)(wp + off); off += 256;

  // prologue: casts, Zt build (in place), init
  cast_f32_bf16<<<8192, 256, 0, stream>>>(x, XZ, NB * NI * NT);
  cast_f32_bf16<<<512, 256, 0, stream>>>(W_attn, Wa, NI * 1024);
  cast_f32_bf16<<<512, 256, 0, stream>>>(W_hh, Whh, NG * 512);
  cast_f32_bf16<<<512, 256, 0, stream>>>(W_comb, Wc, NH * 1024);
  cast_f32_bf16<<<512, 256, 0, stream>>>(W_ih, Wih, NG * 512);
  cast_f32_bf16<<<512, 256, 0, stream>>>(W_out, Wout, 512 * 512);
  zt_inplace<<<4096, 256, 0, stream>>>(XZ, Wc);
  init_kernel<<<512, 256, 0, stream>>>(x, Xt, Hbf, hbuf, bar);

  KParams prm;
  prm.XZ = XZ; prm.Wa = Wa; prm.Whh = Whh; prm.Wc = Wc; prm.Wih = Wih; prm.Wout = Wout;
  prm.Xt = Xt; prm.Hbf = Hbf; prm.Gbf = Gbf;
  prm.logits = logits; prm.gh = gh; prm.gx = gx; prm.hbuf = hbuf;
  prm.x = x; prm.b_attn = b_attn; prm.b_hh = b_hh; prm.b_ih = b_ih; prm.b_out = b_out;
  prm.b_comb = b_comb;
  prm.out = (float*)d_out;
  prm.bar = bar;

  void* kargs[] = { &prm };
  hipError_t e = hipLaunchCooperativeKernel((const void*)persistent_kernel,
                                            dim3(NBLK), dim3(256), kargs, 0, stream);
  if (e != hipSuccess) {
    // barrier is hand-rolled (ws-based), so a plain launch also works: 512 blocks
    // at 2 blocks/CU (enforced by __launch_bounds__(256,2)) are co-resident.
    persistent_kernel<<<dim3(NBLK), dim3(256), 0, stream>>>(prm);
  }
}

// Round 4
// 49132.007 us; speedup vs baseline: 4.8943x; 4.8943x over previous
//
#include <hip/hip_runtime.h>

#define NB 256    // batch
#define NT 512    // T == MAXLEN
#define NI 512    // INPUTS == M
#define NH 512    // HIDDEN
#define NG 1536   // 3*H
#define NBLK 512  // persistent grid

typedef __attribute__((ext_vector_type(8))) short bf16x8;
typedef __attribute__((ext_vector_type(4))) float f32x4;

#define MFMA(a, b, c) __builtin_amdgcn_mfma_f32_16x16x32_bf16((a), (b), (c), 0, 0, 0)

__device__ __forceinline__ unsigned short f2bf(float f) {
  unsigned int u = __float_as_uint(f);
  u = u + 0x7FFFu + ((u >> 16) & 1u);
  return (unsigned short)(u >> 16);
}
__device__ __forceinline__ float bflo(unsigned int p) { return __uint_as_float(p << 16); }
__device__ __forceinline__ float bfhi(unsigned int p) { return __uint_as_float(p & 0xffff0000u); }
__device__ __forceinline__ float sigm(float x) { return 1.f / (1.f + __expf(-x)); }

// ---- device-coherent (LLC, sc1) access helpers: relaxed agent-scope atomics ----
__device__ __forceinline__ float ldf(const float* p) {
  return __hip_atomic_load((const float*)p, __ATOMIC_RELAXED, __HIP_MEMORY_SCOPE_AGENT);
}
__device__ __forceinline__ void stf(float* p, float v) {
  __hip_atomic_store(p, v, __ATOMIC_RELAXED, __HIP_MEMORY_SCOPE_AGENT);
}
__device__ __forceinline__ unsigned long long ldu64(const void* p) {
  return __hip_atomic_load((const unsigned long long*)p, __ATOMIC_RELAXED, __HIP_MEMORY_SCOPE_AGENT);
}
__device__ __forceinline__ void stu64(void* p, unsigned long long v) {
  __hip_atomic_store((unsigned long long*)p, v, __ATOMIC_RELAXED, __HIP_MEMORY_SCOPE_AGENT);
}
__device__ __forceinline__ void stu32(void* p, unsigned v) {
  __hip_atomic_store((unsigned*)p, v, __ATOMIC_RELAXED, __HIP_MEMORY_SCOPE_AGENT);
}
// 16B bf16 fragment via two pipelined 8B sc1 loads
__device__ __forceinline__ bf16x8 ld_frag(const unsigned short* p) {
  union { unsigned long long q[2]; bf16x8 f; } u;
  u.q[0] = ldu64(p);
  u.q[1] = ldu64(p + 4);
  return u.f;
}

// ---------------- generic f32 -> bf16 cast ----------------
__global__ __launch_bounds__(256) void cast_f32_bf16(const float* __restrict__ s,
                                                     unsigned short* __restrict__ d, int n) {
  int i = blockIdx.x * 256 + threadIdx.x;
  int stride = gridDim.x * 256;
  for (; i < n; i += stride) d[i] = f2bf(s[i]);
}

// ---------------- Zt = (bf16 X) @ Wc2^T, in place over Xc ----------------
__global__ __launch_bounds__(256) void zt_inplace(unsigned short* __restrict__ XZ,
                                                  const unsigned short* __restrict__ Wc) {
  __shared__ unsigned short As[32][552];
  const int tid = threadIdx.x;
  const int row0 = blockIdx.x * 32;
  const uint4* src = (const uint4*)(XZ + (size_t)row0 * 512);
#pragma unroll
  for (int it = 0; it < 8; ++it) {
    int e8 = tid + it * 256;
    uint4 v = src[e8];
    *(uint4*)&As[e8 >> 6][(e8 & 63) * 8] = v;
  }
  __syncthreads();
  const int lane = tid & 63, w = tid >> 6;
  const int al = lane & 15, kg = lane >> 4;
  const int rbase = (w & 1) * 16;
  const int cbase = (w >> 1) * 256;
  for (int cc = 0; cc < 16; ++cc) {
    int col0 = cbase + cc * 16;
    f32x4 acc = {0.f, 0.f, 0.f, 0.f};
    const unsigned short* Bp = Wc + (size_t)(col0 + al) * 1024 + 512;
    for (int k = 0; k < 512; k += 32) {
      bf16x8 av = *(const bf16x8*)&As[rbase + al][k + kg * 8];
      bf16x8 bv = *(const bf16x8*)(Bp + k + kg * 8);
      acc = MFMA(av, bv, acc);
    }
#pragma unroll
    for (int r = 0; r < 4; ++r) {
      int row = row0 + rbase + kg * 4 + r;
      XZ[(size_t)row * 512 + col0 + al] = f2bf(acc[r]);
    }
  }
}

// ---------------- init: Xt slot0 = x[:, :, 0], Hbf = 0, barrier block = 0 ----------------
__global__ __launch_bounds__(256) void init_kernel(const float* __restrict__ x,
                                                   unsigned short* __restrict__ Xt,
                                                   unsigned short* __restrict__ Hbf,
                                                   unsigned* __restrict__ bar) {
  int idx = blockIdx.x * 256 + threadIdx.x;
  if (idx < 1024) bar[idx] = 0u;
  if (idx < NB * NI) {
    int b = idx >> 9, i = idx & 511;
    Xt[idx] = f2bf(x[((size_t)b * 512 + i) * 512]);
    Hbf[idx] = 0;
  }
}

struct KParams {
  const unsigned short* XZ;   // Zt [b][m][h] bf16
  const unsigned short* Wa;   // [512][1024]
  const unsigned short* Whh;  // [1536][512]
  const unsigned short* Wc;   // [512][1024]
  const unsigned short* Wih;  // [1536][512]
  const unsigned short* Wout; // [512][512]
  unsigned short* Xt;         // [2][256][512] bf16 x_t double buffer (cc)
  unsigned short* Hbf;        // [256][512] bf16 h (cc)
  unsigned short* Gbf;        // [256][512] bf16 g (cc)
  float* logits;              // [256][512] (cc)
  float* gh;                  // [256][1536] (cc)
  float* gx;                  // [256][512] (cc)
  const float* x;
  const float* b_attn;
  const float* b_hh;
  const float* b_ih;
  const float* b_comb;
  const float* b_out;
  float* out;
  unsigned* bar;
};

// monotonic tree barrier: bar[0..7*64] group counters (256B apart),
// bar[512] root, bar[576] generation. All relaxed agent-scope (sc1), no fences.
// Safe because generation-flip gates the next round's arrivals.
__device__ __forceinline__ void gbar(unsigned* bar, unsigned gen_expect) {
  asm volatile("s_waitcnt vmcnt(0)" ::: "memory");  // this wave's sc1 stores at LLC
  __syncthreads();                                  // drains all waves' vmem + block sync
  if (threadIdx.x == 0) {
    unsigned old = __hip_atomic_fetch_add(&bar[(blockIdx.x >> 6) * 64], 1u,
                                          __ATOMIC_RELAXED, __HIP_MEMORY_SCOPE_AGENT);
    if ((old & 63) == 63) {
      unsigned ro = __hip_atomic_fetch_add(&bar[512], 1u,
                                           __ATOMIC_RELAXED, __HIP_MEMORY_SCOPE_AGENT);
      if ((ro & 7) == 7)
        __hip_atomic_fetch_add(&bar[576], 1u,
                               __ATOMIC_RELAXED, __HIP_MEMORY_SCOPE_AGENT);
    }
    while (__hip_atomic_load(&bar[576], __ATOMIC_RELAXED, __HIP_MEMORY_SCOPE_AGENT) < gen_expect)
      __builtin_amdgcn_s_sleep(4);
    asm volatile("" ::: "memory");
  }
  __syncthreads();
}

__global__ __launch_bounds__(256, 2) void persistent_kernel(KParams P) {
  __shared__ float aw[512];
  __shared__ float4 part[4][64];
  __shared__ float red[8];
  const int bid = blockIdx.x, tid = threadIdx.x;
  const int lane = tid & 63, w = tid >> 6;
  const int al = lane & 15, kg = lane >> 4;

  f32x4 hreg = {0.f, 0.f, 0.f, 0.f};   // P3 h carry (f32), static (row,j) ownership

  for (int t = 0; t < NT; ++t) {
    const int p = t & 1, np = p ^ 1;
    // ================= P1: logits | gh | gx | gather x_{t+1} =================
    if (bid < 64) {
      // logits = [xt|h] @ Wa^T + b_attn : tile 64r x 32c
      int rt = bid >> 4, ct = bid & 15;
      int row0 = rt * 64 + w * 16, col0 = ct * 32;
      const unsigned short* Ax = P.Xt + (size_t)p * (NB * NI) + (size_t)(row0 + al) * NI;
      const unsigned short* Ah = P.Hbf + (size_t)(row0 + al) * NH;
      const unsigned short* B0 = P.Wa + (size_t)(col0 + al) * 1024;
      const unsigned short* B1 = P.Wa + (size_t)(col0 + 16 + al) * 1024;
      f32x4 a0 = {0.f, 0.f, 0.f, 0.f}, a1 = {0.f, 0.f, 0.f, 0.f};
      for (int k = 0; k < 512; k += 32) {
        bf16x8 av = ld_frag(Ax + k + kg * 8);
        a0 = MFMA(av, *(const bf16x8*)(B0 + k + kg * 8), a0);
        a1 = MFMA(av, *(const bf16x8*)(B1 + k + kg * 8), a1);
      }
      for (int k = 0; k < 512; k += 32) {
        bf16x8 av = ld_frag(Ah + k + kg * 8);
        a0 = MFMA(av, *(const bf16x8*)(B0 + 512 + k + kg * 8), a0);
        a1 = MFMA(av, *(const bf16x8*)(B1 + 512 + k + kg * 8), a1);
      }
#pragma unroll
      for (int r = 0; r < 4; ++r) {
        int row = row0 + kg * 4 + r;
        stf(&P.logits[row * NI + col0 + al], a0[r] + P.b_attn[col0 + al]);
        stf(&P.logits[row * NI + col0 + 16 + al], a1[r] + P.b_attn[col0 + 16 + al]);
      }
    } else if (bid < 256) {
      // gh = h @ Whh^T + b_hh : tile 64r x 32c of 1536
      int b2 = bid - 64;
      int rt = b2 / 48, ct = b2 % 48;
      int row0 = rt * 64 + w * 16, col0 = ct * 32;
      const unsigned short* Ah = P.Hbf + (size_t)(row0 + al) * NH;
      const unsigned short* B0 = P.Whh + (size_t)(col0 + al) * 512;
      const unsigned short* B1 = P.Whh + (size_t)(col0 + 16 + al) * 512;
      f32x4 a0 = {0.f, 0.f, 0.f, 0.f}, a1 = {0.f, 0.f, 0.f, 0.f};
      for (int k = 0; k < 512; k += 32) {
        bf16x8 av = ld_frag(Ah + k + kg * 8);
        a0 = MFMA(av, *(const bf16x8*)(B0 + k + kg * 8), a0);
        a1 = MFMA(av, *(const bf16x8*)(B1 + k + kg * 8), a1);
      }
#pragma unroll
      for (int r = 0; r < 4; ++r) {
        int row = row0 + kg * 4 + r;
        stf(&P.gh[row * NG + col0 + al], a0[r] + P.b_hh[col0 + al]);
        stf(&P.gh[row * NG + col0 + 16 + al], a1[r] + P.b_hh[col0 + 16 + al]);
      }
    } else if (bid < 320) {
      // gx = xt @ Wc1^T + b_comb : tile 64r x 32c
      int b3 = bid - 256;
      int rt = b3 >> 4, ct = b3 & 15;
      int row0 = rt * 64 + w * 16, col0 = ct * 32;
      const unsigned short* Ax = P.Xt + (size_t)p * (NB * NI) + (size_t)(row0 + al) * NI;
      const unsigned short* B0 = P.Wc + (size_t)(col0 + al) * 1024;
      const unsigned short* B1 = P.Wc + (size_t)(col0 + 16 + al) * 1024;
      f32x4 a0 = {0.f, 0.f, 0.f, 0.f}, a1 = {0.f, 0.f, 0.f, 0.f};
      for (int k = 0; k < 512; k += 32) {
        bf16x8 av = ld_frag(Ax + k + kg * 8);
        a0 = MFMA(av, *(const bf16x8*)(B0 + k + kg * 8), a0);
        a1 = MFMA(av, *(const bf16x8*)(B1 + k + kg * 8), a1);
      }
#pragma unroll
      for (int r = 0; r < 4; ++r) {
        int row = row0 + kg * 4 + r;
        stf(&P.gx[row * NH + col0 + al], a0[r] + P.b_comb[col0 + al]);
        stf(&P.gx[row * NH + col0 + 16 + al], a1[r] + P.b_comb[col0 + 16 + al]);
      }
    } else {
      // gather x_{t+1} column into Xt[np], paired (4B cc stores)
      if (t < NT - 1) {
        for (int e2 = (bid - 320) * 256 + tid; e2 < NB * NI / 2; e2 += 192 * 256) {
          int b = e2 >> 8, i = (e2 & 255) * 2;
          const float* xp = P.x + ((size_t)b * 512 + i) * 512 + t + 1;
          unsigned lo = f2bf(xp[0]);
          unsigned hi = f2bf(xp[512]);
          stu32(&P.Xt[(size_t)np * (NB * NI) + b * 512 + i], lo | (hi << 16));
        }
      }
    }
    gbar(P.bar, 3 * t + 1);

    // ================= P2: softmax + Zt-stream -> g =================
    {
      const int b = bid >> 1, half = bid & 1;
      union { unsigned long long q; float2 v; } L;
      L.q = ldu64((const float2*)(P.logits + (size_t)b * NI) + tid);
      float2 lv = L.v;
      float mx = fmaxf(lv.x, lv.y);
#pragma unroll
      for (int off = 32; off >= 1; off >>= 1) mx = fmaxf(mx, __shfl_xor(mx, off));
      if (lane == 0) red[w] = mx;
      __syncthreads();
      mx = fmaxf(fmaxf(red[0], red[1]), fmaxf(red[2], red[3]));
      float e0 = __expf(lv.x - mx), e1 = __expf(lv.y - mx);
      float sm = e0 + e1;
#pragma unroll
      for (int off = 32; off >= 1; off >>= 1) sm += __shfl_xor(sm, off);
      if (lane == 0) red[4 + w] = sm;
      __syncthreads();
      sm = (red[4] + red[5]) + (red[6] + red[7]);
      float inv = 1.f / sm;
      aw[2 * tid] = e0 * inv;
      aw[2 * tid + 1] = e1 * inv;
      __syncthreads();

      // stream Zt[b][m][h-quad] (plain loads: read-only, L2-cacheable)
      const uint2* X2 = (const uint2*)P.XZ + ((size_t)b << 16) + half * 64 + lane;
      float4 c = {0.f, 0.f, 0.f, 0.f};
      for (int mi = 0; mi < 128; mi += 16) {
        uint2 px[16];
        float av_[16];
#pragma unroll
        for (int u = 0; u < 16; ++u) px[u] = X2[(size_t)((mi + u) * 4 + w) * 128];
#pragma unroll
        for (int u = 0; u < 16; ++u) av_[u] = aw[(mi + u) * 4 + w];
#pragma unroll
        for (int u = 0; u < 16; ++u) {
          c.x = fmaf(av_[u], bflo(px[u].x), c.x);
          c.y = fmaf(av_[u], bfhi(px[u].x), c.y);
          c.z = fmaf(av_[u], bflo(px[u].y), c.z);
          c.w = fmaf(av_[u], bfhi(px[u].y), c.w);
        }
      }
      part[w][lane] = c;
      __syncthreads();
      if (w == 0) {
        float4 s0 = part[0][lane], s1 = part[1][lane], s2 = part[2][lane], s3 = part[3][lane];
        int h0 = half * 256 + lane * 4;
        union { unsigned long long q; float f[2]; } ga, gb;
        ga.q = ldu64(P.gx + (size_t)b * NH + h0);
        gb.q = ldu64(P.gx + (size_t)b * NH + h0 + 2);
        float v0 = fmaxf(ga.f[0] + ((s0.x + s1.x) + (s2.x + s3.x)), 0.f);
        float v1 = fmaxf(ga.f[1] + ((s0.y + s1.y) + (s2.y + s3.y)), 0.f);
        float v2 = fmaxf(gb.f[0] + ((s0.z + s1.z) + (s2.z + s3.z)), 0.f);
        float v3 = fmaxf(gb.f[1] + ((s0.w + s1.w) + (s2.w + s3.w)), 0.f);
        unsigned long long o =
            (unsigned long long)((unsigned)f2bf(v0) | ((unsigned)f2bf(v1) << 16)) |
            ((unsigned long long)((unsigned)f2bf(v2) | ((unsigned)f2bf(v3) << 16)) << 32);
        stu64(P.Gbf + (size_t)b * NH + h0, o);
      }
    }
    gbar(P.bar, 3 * t + 2);

    // ================= P3: GRU gates -> h' =================
    if (bid < 128) {
      int rt = bid >> 4, ct = bid & 15;
      int row0 = rt * 32 + (w & 1) * 16;
      int j0 = ct * 32 + (w >> 1) * 16;
      const unsigned short* Ag = P.Gbf + (size_t)(row0 + al) * NH;
      const unsigned short* Br = P.Wih + (size_t)(j0 + al) * 512;
      const unsigned short* Bz = P.Wih + (size_t)(j0 + 512 + al) * 512;
      const unsigned short* Bn = P.Wih + (size_t)(j0 + 1024 + al) * 512;
      f32x4 ar = {0.f, 0.f, 0.f, 0.f}, az = {0.f, 0.f, 0.f, 0.f}, an = {0.f, 0.f, 0.f, 0.f};
      for (int k = 0; k < 512; k += 32) {
        bf16x8 av = ld_frag(Ag + k + kg * 8);
        ar = MFMA(av, *(const bf16x8*)(Br + k + kg * 8), ar);
        az = MFMA(av, *(const bf16x8*)(Bz + k + kg * 8), az);
        an = MFMA(av, *(const bf16x8*)(Bn + k + kg * 8), an);
      }
      int j = j0 + al;
      float bir = P.b_ih[j], biz = P.b_ih[j + 512], bin_ = P.b_ih[j + 1024];
#pragma unroll
      for (int r = 0; r < 4; ++r) {
        int row = row0 + kg * 4 + r;
        float ghr = ldf(&P.gh[(size_t)row * NG + j]);
        float ghz = ldf(&P.gh[(size_t)row * NG + j + 512]);
        float ghn = ldf(&P.gh[(size_t)row * NG + j + 1024]);
        float rg = sigm(ar[r] + bir + ghr);
        float zg = sigm(az[r] + biz + ghz);
        float ng = tanhf(an[r] + bin_ + rg * ghn);
        float hn = (1.f - zg) * ng + zg * hreg[r];
        hreg[r] = hn;
        // pack bf16 pair with lane-neighbor, 4B cc store from even sub-lane
        unsigned hv = f2bf(hn);
        unsigned ov = __shfl_xor((int)hv, 1);
        if ((al & 1) == 0)
          stu32(&P.Hbf[(size_t)row * NH + (j & ~1)], hv | (ov << 16));
      }
    }
    gbar(P.bar, 3 * t + 3);
  }

  // ================= P5: out = h_T @ Wout^T + b_out =================
  if (bid < 128) {
    int rt = bid >> 4, ct = bid & 15;
    int row0 = rt * 32 + (w & 1) * 16;
    int col0 = ct * 32 + (w >> 1) * 16;
    const unsigned short* Ah = P.Hbf + (size_t)(row0 + al) * NH;
    const unsigned short* B0 = P.Wout + (size_t)(col0 + al) * 512;
    f32x4 acc = {0.f, 0.f, 0.f, 0.f};
    for (int k = 0; k < 512; k += 32) {
      bf16x8 av = ld_frag(Ah + k + kg * 8);
      acc = MFMA(av, *(const bf16x8*)(B0 + k + kg * 8), acc);
    }
#pragma unroll
    for (int r = 0; r < 4; ++r) {
      int row = row0 + kg * 4 + r;
      P.out[row * 512 + col0 + al] = acc[r] + P.b_out[col0 + al];
    }
  }
}

extern "C" void kernel_launch(void* const* d_in, const int* in_sizes, int n_in,
                              void* d_out, int out_size, void* d_ws, size_t ws_size,
                              hipStream_t stream) {
  const float* x      = (const float*)d_in[0];
  const float* W_attn = (const float*)d_in[1];
  const float* b_attn = (const float*)d_in[2];
  const float* W_comb = (const float*)d_in[3];
  const float* b_comb = (const float*)d_in[4];
  const float* W_ih   = (const float*)d_in[5];
  const float* W_hh   = (const float*)d_in[6];
  const float* b_ih   = (const float*)d_in[7];
  const float* b_hh   = (const float*)d_in[8];
  const float* W_out  = (const float*)d_in[9];
  const float* b_out  = (const float*)d_in[10];

  char* wp = (char*)d_ws;
  size_t off = 0;
  unsigned short* XZ   = (unsigned short*)(wp + off); off += (size_t)NB * NI * NH * 2;   // 128MB (Xc then Zt)
  unsigned short* Wa   = (unsigned short*)(wp + off); off += (size_t)NI * 1024 * 2;
  unsigned short* Whh  = (unsigned short*)(wp + off); off += (size_t)NG * 512 * 2;
  unsigned short* Wc   = (unsigned short*)(wp + off); off += (size_t)NH * 1024 * 2;
  unsigned short* Wih  = (unsigned short*)(wp + off); off += (size_t)NG * 512 * 2;
  unsigned short* Wout = (unsigned short*)(wp + off); off += (size_t)512 * 512 * 2;
  unsigned short* Xt   = (unsigned short*)(wp + off); off += (size_t)2 * NB * NI * 2;
  unsigned short* Hbf  = (unsigned short*)(wp + off); off += (size_t)NB * NH * 2;
  unsigned short* Gbf  = (unsigned short*)(wp + off); off += (size_t)NB * NH * 2;
  float* logits        = (float*)(wp + off); off += (size_t)NB * NI * 4;
  float* gh            = (float*)(wp + off); off += (size_t)NB * NG * 4;
  float* gx            = (float*)(wp + off); off += (size_t)NB * NH * 4;
  unsigned* bar        = (unsigned*)(wp + off); off += 4096;

  // prologue: casts, Zt build (in place), init
  cast_f32_bf16<<<8192, 256, 0, stream>>>(x, XZ, NB * NI * NT);
  cast_f32_bf16<<<512, 256, 0, stream>>>(W_attn, Wa, NI * 1024);
  cast_f32_bf16<<<512, 256, 0, stream>>>(W_hh, Whh, NG * 512);
  cast_f32_bf16<<<512, 256, 0, stream>>>(W_comb, Wc, NH * 1024);
  cast_f32_bf16<<<512, 256, 0, stream>>>(W_ih, Wih, NG * 512);
  cast_f32_bf16<<<512, 256, 0, stream>>>(W_out, Wout, 512 * 512);
  zt_inplace<<<4096, 256, 0, stream>>>(XZ, Wc);
  init_kernel<<<512, 256, 0, stream>>>(x, Xt, Hbf, bar);

  KParams prm;
  prm.XZ = XZ; prm.Wa = Wa; prm.Whh = Whh; prm.Wc = Wc; prm.Wih = Wih; prm.Wout = Wout;
  prm.Xt = Xt; prm.Hbf = Hbf; prm.Gbf = Gbf;
  prm.logits = logits; prm.gh = gh; prm.gx = gx;
  prm.x = x; prm.b_attn = b_attn; prm.b_hh = b_hh; prm.b_ih = b_ih; prm.b_out = b_out;
  prm.b_comb = b_comb;
  prm.out = (float*)d_out;
  prm.bar = bar;

  void* kargs[] = { &prm };
  hipError_t e = hipLaunchCooperativeKernel((const void*)persistent_kernel,
                                            dim3(NBLK), dim3(256), kargs, 0, stream);
  if (e != hipSuccess) {
    persistent_kernel<<<dim3(NBLK), dim3(256), 0, stream>>>(prm);
  }
}

// Round 5
// 39033.679 us; speedup vs baseline: 6.1605x; 1.2587x over previous
//
#include <hip/hip_runtime.h>

#define NB 256    // batch
#define NT 512    // T == MAXLEN
#define NI 512    // INPUTS == M
#define NH 512    // HIDDEN
#define NG 1536   // 3*H
#define NBLK 512  // persistent grid

typedef __attribute__((ext_vector_type(8))) short bf16x8;
typedef __attribute__((ext_vector_type(4))) float f32x4;

#define MFMA(a, b, c) __builtin_amdgcn_mfma_f32_16x16x32_bf16((a), (b), (c), 0, 0, 0)

__device__ __forceinline__ unsigned short f2bf(float f) {
  unsigned int u = __float_as_uint(f);
  u = u + 0x7FFFu + ((u >> 16) & 1u);
  return (unsigned short)(u >> 16);
}
__device__ __forceinline__ float bflo(unsigned int p) { return __uint_as_float(p << 16); }
__device__ __forceinline__ float bfhi(unsigned int p) { return __uint_as_float(p & 0xffff0000u); }
__device__ __forceinline__ float sigm(float x) { return 1.f / (1.f + __expf(-x)); }

// ---- device-coherent (LLC, sc1) access helpers: relaxed agent-scope atomics ----
__device__ __forceinline__ float ldf(const float* p) {
  return __hip_atomic_load((const float*)p, __ATOMIC_RELAXED, __HIP_MEMORY_SCOPE_AGENT);
}
__device__ __forceinline__ void stf(float* p, float v) {
  __hip_atomic_store(p, v, __ATOMIC_RELAXED, __HIP_MEMORY_SCOPE_AGENT);
}
__device__ __forceinline__ unsigned ldu32(const unsigned* p) {
  return __hip_atomic_load(p, __ATOMIC_RELAXED, __HIP_MEMORY_SCOPE_AGENT);
}
__device__ __forceinline__ void stu32(void* p, unsigned v) {
  __hip_atomic_store((unsigned*)p, v, __ATOMIC_RELAXED, __HIP_MEMORY_SCOPE_AGENT);
}
__device__ __forceinline__ unsigned long long ldu64(const void* p) {
  return __hip_atomic_load((const unsigned long long*)p, __ATOMIC_RELAXED, __HIP_MEMORY_SCOPE_AGENT);
}
__device__ __forceinline__ void stu64(void* p, unsigned long long v) {
  __hip_atomic_store((unsigned long long*)p, v, __ATOMIC_RELAXED, __HIP_MEMORY_SCOPE_AGENT);
}
// 16B bf16 fragment via two 8B sc1 loads (issued back-to-back when batched)
__device__ __forceinline__ bf16x8 ld_frag(const unsigned short* p) {
  union { unsigned long long q[2]; bf16x8 f; } u;
  u.q[0] = ldu64(p);
  u.q[1] = ldu64(p + 4);
  return u.f;
}

// ---------------- generic f32 -> bf16 cast ----------------
__global__ __launch_bounds__(256) void cast_f32_bf16(const float* __restrict__ s,
                                                     unsigned short* __restrict__ d, int n) {
  int i = blockIdx.x * 256 + threadIdx.x;
  int stride = gridDim.x * 256;
  for (; i < n; i += stride) d[i] = f2bf(s[i]);
}

// ---------------- Zt = (bf16 X) @ Wc2^T, in place over Xc ----------------
__global__ __launch_bounds__(256) void zt_inplace(unsigned short* __restrict__ XZ,
                                                  const unsigned short* __restrict__ Wc) {
  __shared__ unsigned short As[32][552];
  const int tid = threadIdx.x;
  const int row0 = blockIdx.x * 32;
  const uint4* src = (const uint4*)(XZ + (size_t)row0 * 512);
#pragma unroll
  for (int it = 0; it < 8; ++it) {
    int e8 = tid + it * 256;
    uint4 v = src[e8];
    *(uint4*)&As[e8 >> 6][(e8 & 63) * 8] = v;
  }
  __syncthreads();
  const int lane = tid & 63, w = tid >> 6;
  const int al = lane & 15, kg = lane >> 4;
  const int rbase = (w & 1) * 16;
  const int cbase = (w >> 1) * 256;
  for (int cc = 0; cc < 16; ++cc) {
    int col0 = cbase + cc * 16;
    f32x4 acc = {0.f, 0.f, 0.f, 0.f};
    const unsigned short* Bp = Wc + (size_t)(col0 + al) * 1024 + 512;
    for (int k = 0; k < 512; k += 32) {
      bf16x8 av = *(const bf16x8*)&As[rbase + al][k + kg * 8];
      bf16x8 bv = *(const bf16x8*)(Bp + k + kg * 8);
      acc = MFMA(av, bv, acc);
    }
#pragma unroll
    for (int r = 0; r < 4; ++r) {
      int row = row0 + rbase + kg * 4 + r;
      XZ[(size_t)row * 512 + col0 + al] = f2bf(acc[r]);
    }
  }
}

// ---------------- init: Xt slot0 = x[:, :, 0], Hbf = 0, barrier+flags = 0 ----------------
__global__ __launch_bounds__(256) void init_kernel(const float* __restrict__ x,
                                                   unsigned short* __restrict__ Xt,
                                                   unsigned short* __restrict__ Hbf,
                                                   unsigned* __restrict__ bar) {
  int idx = blockIdx.x * 256 + threadIdx.x;
  if (idx < 1024) bar[idx] = 0u;
  if (idx < NB * NI) {
    int b = idx >> 9, i = idx & 511;
    Xt[idx] = f2bf(x[((size_t)b * 512 + i) * 512]);
    Hbf[idx] = 0;
  }
}

struct KParams {
  const unsigned short* XZ;   // Zt [b][m][h] bf16 (row-major, h contiguous)
  const unsigned short* Wa;   // [512][1024]
  const unsigned short* Whh;  // [1536][512]
  const unsigned short* Wc;   // [512][1024]
  const unsigned short* Wih;  // [1536][512]
  const unsigned short* Wout; // [512][512]
  unsigned short* Xt;         // [2][256][512] bf16 x_t double buffer (cc)
  unsigned short* Hbf;        // [256][512] bf16 h (cc)
  unsigned short* Gbf;        // [256][512] bf16 g (cc)
  float* logits;              // [256][512] (cc)
  float* gh;                  // [256][1536] (cc)
  float* gx;                  // [256][512] (cc)
  float* Gp;                  // [256][512] f32 partial ctx (m-half 0) (cc)
  const float* x;
  const float* b_attn;
  const float* b_hh;
  const float* b_ih;
  const float* b_comb;
  const float* b_out;
  float* out;
  unsigned* bar;
};

// monotonic tree barrier (relaxed agent-scope atomics, no fences; sc1 data stores
// are already at the LLC once each block's vmcnt is drained before arrival)
__device__ __forceinline__ void gbar(unsigned* bar, unsigned gen_expect) {
  asm volatile("s_waitcnt vmcnt(0)" ::: "memory");
  __syncthreads();
  if (threadIdx.x == 0) {
    unsigned old = __hip_atomic_fetch_add(&bar[(blockIdx.x >> 6) * 64], 1u,
                                          __ATOMIC_RELAXED, __HIP_MEMORY_SCOPE_AGENT);
    if ((old & 63) == 63) {
      unsigned ro = __hip_atomic_fetch_add(&bar[512], 1u,
                                           __ATOMIC_RELAXED, __HIP_MEMORY_SCOPE_AGENT);
      if ((ro & 7) == 7)
        __hip_atomic_fetch_add(&bar[576], 1u,
                               __ATOMIC_RELAXED, __HIP_MEMORY_SCOPE_AGENT);
    }
    while (__hip_atomic_load(&bar[576], __ATOMIC_RELAXED, __HIP_MEMORY_SCOPE_AGENT) < gen_expect)
      __builtin_amdgcn_s_sleep(4);
    asm volatile("" ::: "memory");
  }
  __syncthreads();
}

__global__ __launch_bounds__(256, 2) void persistent_kernel(KParams P) {
  __shared__ float aw[512];
  __shared__ float4 pA[4][64];
  __shared__ float4 pB[4][64];
  __shared__ float red[8];
  const int bid = blockIdx.x, tid = threadIdx.x;
  const int lane = tid & 63, w = tid >> 6;
  const int al = lane & 15, kg = lane >> 4;

  f32x4 hreg = {0.f, 0.f, 0.f, 0.f};   // P3 h carry (f32), static (row,j) ownership

  for (int t = 0; t < NT; ++t) {
    const int p = t & 1, np = p ^ 1;
    // ========== P1: logits[0,128) | gh[128,320) | gx[320,384) | gather[384,512) ==========
    if (bid < 128) {
      // logits = [xt|h] @ Wa^T + b_attn : 32r x 32c tile, wave = 16x16, K=1024
      int rt = bid >> 4, ct = bid & 15;
      int row0 = rt * 32 + (w & 1) * 16, col0 = ct * 32 + (w >> 1) * 16;
      const unsigned short* Ax = P.Xt + (size_t)p * (NB * NI) + (size_t)(row0 + al) * NI;
      const unsigned short* Ah = P.Hbf + (size_t)(row0 + al) * NH;
      const unsigned short* B = P.Wa + (size_t)(col0 + al) * 1024;
      f32x4 a0 = {0.f, 0.f, 0.f, 0.f};
      bf16x8 frA[16];
#pragma unroll
      for (int i = 0; i < 16; ++i) frA[i] = ld_frag(Ax + i * 32 + kg * 8);
#pragma unroll
      for (int i = 0; i < 16; ++i) a0 = MFMA(frA[i], *(const bf16x8*)(B + i * 32 + kg * 8), a0);
#pragma unroll
      for (int i = 0; i < 16; ++i) frA[i] = ld_frag(Ah + i * 32 + kg * 8);
#pragma unroll
      for (int i = 0; i < 16; ++i) a0 = MFMA(frA[i], *(const bf16x8*)(B + 512 + i * 32 + kg * 8), a0);
#pragma unroll
      for (int r = 0; r < 4; ++r) {
        int row = row0 + kg * 4 + r;
        stf(&P.logits[row * NI + col0 + al], a0[r] + P.b_attn[col0 + al]);
      }
    } else if (bid < 320) {
      // gh = h @ Whh^T + b_hh : 64r x 32c tile, wave = 16r x 32c, K=512
      int b2 = bid - 128;
      int rt = b2 / 48, ct = b2 % 48;
      int row0 = rt * 64 + w * 16, col0 = ct * 32;
      const unsigned short* Ah = P.Hbf + (size_t)(row0 + al) * NH;
      const unsigned short* B0 = P.Whh + (size_t)(col0 + al) * 512;
      const unsigned short* B1 = P.Whh + (size_t)(col0 + 16 + al) * 512;
      f32x4 a0 = {0.f, 0.f, 0.f, 0.f}, a1 = {0.f, 0.f, 0.f, 0.f};
      bf16x8 frA[16];
#pragma unroll
      for (int i = 0; i < 16; ++i) frA[i] = ld_frag(Ah + i * 32 + kg * 8);
#pragma unroll
      for (int i = 0; i < 16; ++i) {
        a0 = MFMA(frA[i], *(const bf16x8*)(B0 + i * 32 + kg * 8), a0);
        a1 = MFMA(frA[i], *(const bf16x8*)(B1 + i * 32 + kg * 8), a1);
      }
#pragma unroll
      for (int r = 0; r < 4; ++r) {
        int row = row0 + kg * 4 + r;
        stf(&P.gh[row * NG + col0 + al], a0[r] + P.b_hh[col0 + al]);
        stf(&P.gh[row * NG + col0 + 16 + al], a1[r] + P.b_hh[col0 + 16 + al]);
      }
    } else if (bid < 384) {
      // gx = xt @ Wc1^T + b_comb : 64r x 32c tile, K=512
      int b3 = bid - 320;
      int rt = b3 >> 4, ct = b3 & 15;
      int row0 = rt * 64 + w * 16, col0 = ct * 32;
      const unsigned short* Ax = P.Xt + (size_t)p * (NB * NI) + (size_t)(row0 + al) * NI;
      const unsigned short* B0 = P.Wc + (size_t)(col0 + al) * 1024;
      const unsigned short* B1 = P.Wc + (size_t)(col0 + 16 + al) * 1024;
      f32x4 a0 = {0.f, 0.f, 0.f, 0.f}, a1 = {0.f, 0.f, 0.f, 0.f};
      bf16x8 frA[16];
#pragma unroll
      for (int i = 0; i < 16; ++i) frA[i] = ld_frag(Ax + i * 32 + kg * 8);
#pragma unroll
      for (int i = 0; i < 16; ++i) {
        a0 = MFMA(frA[i], *(const bf16x8*)(B0 + i * 32 + kg * 8), a0);
        a1 = MFMA(frA[i], *(const bf16x8*)(B1 + i * 32 + kg * 8), a1);
      }
#pragma unroll
      for (int r = 0; r < 4; ++r) {
        int row = row0 + kg * 4 + r;
        stf(&P.gx[row * NH + col0 + al], a0[r] + P.b_comb[col0 + al]);
        stf(&P.gx[row * NH + col0 + 16 + al], a1[r] + P.b_comb[col0 + 16 + al]);
      }
    } else {
      // gather x_{t+1} into Xt[np], paired stores
      if (t < NT - 1) {
        for (int e2 = (bid - 384) * 256 + tid; e2 < NB * NI / 2; e2 += 128 * 256) {
          int b = e2 >> 8, i = (e2 & 255) * 2;
          const float* xp = P.x + ((size_t)b * 512 + i) * 512 + t + 1;
          unsigned lo = f2bf(xp[0]);
          unsigned hi = f2bf(xp[512]);
          stu32(&P.Xt[(size_t)np * (NB * NI) + b * 512 + i], lo | (hi << 16));
        }
      }
    }
    gbar(P.bar, 3 * t + 1);

    // ========== P2: softmax + Zt-stream (block = (b, m-half)) ==========
    {
      const int b = bid >> 1, mh = bid & 1;
      union { unsigned long long q; float2 v; } L;
      L.q = ldu64(P.logits + (size_t)b * NI + 2 * tid);
      float2 lv = L.v;
      float mx = fmaxf(lv.x, lv.y);
#pragma unroll
      for (int off = 32; off >= 1; off >>= 1) mx = fmaxf(mx, __shfl_xor(mx, off));
      if (lane == 0) red[w] = mx;
      __syncthreads();
      mx = fmaxf(fmaxf(red[0], red[1]), fmaxf(red[2], red[3]));
      float e0 = __expf(lv.x - mx), e1 = __expf(lv.y - mx);
      float sm = e0 + e1;
#pragma unroll
      for (int off = 32; off >= 1; off >>= 1) sm += __shfl_xor(sm, off);
      if (lane == 0) red[4 + w] = sm;
      __syncthreads();
      sm = (red[4] + red[5]) + (red[6] + red[7]);
      float inv = 1.f / sm;
      aw[2 * tid] = e0 * inv;
      aw[2 * tid + 1] = e1 * inv;
      __syncthreads();

      // wave w streams rows m = mh*256 + w*64 + [0,64); one wave-load = one 1KB row
      const uint4* Z4 = (const uint4*)P.XZ + (((size_t)b * 512 + mh * 256 + w * 64) << 6) + lane;
      const float* awp = aw + mh * 256 + w * 64;
      float c0 = 0.f, c1 = 0.f, c2 = 0.f, c3 = 0.f, c4 = 0.f, c5 = 0.f, c6 = 0.f, c7 = 0.f;
#pragma unroll
      for (int mm = 0; mm < 64; mm += 16) {
        uint4 px[16];
#pragma unroll
        for (int u = 0; u < 16; ++u) px[u] = Z4[(mm + u) << 6];
#pragma unroll
        for (int u = 0; u < 16; ++u) {
          float a_ = awp[mm + u];
          c0 = fmaf(a_, bflo(px[u].x), c0); c1 = fmaf(a_, bfhi(px[u].x), c1);
          c2 = fmaf(a_, bflo(px[u].y), c2); c3 = fmaf(a_, bfhi(px[u].y), c3);
          c4 = fmaf(a_, bflo(px[u].z), c4); c5 = fmaf(a_, bfhi(px[u].z), c5);
          c6 = fmaf(a_, bflo(px[u].w), c6); c7 = fmaf(a_, bfhi(px[u].w), c7);
        }
      }
      pA[w][lane] = make_float4(c0, c1, c2, c3);
      pB[w][lane] = make_float4(c4, c5, c6, c7);
      __syncthreads();
      float s0_, s1_, s2_, s3_, s4_, s5_, s6_, s7_;
      if (w == 0) {
        float4 a0_ = pA[0][lane], a1_ = pA[1][lane], a2_ = pA[2][lane], a3_ = pA[3][lane];
        float4 b0_ = pB[0][lane], b1_ = pB[1][lane], b2_ = pB[2][lane], b3_ = pB[3][lane];
        s0_ = (a0_.x + a1_.x) + (a2_.x + a3_.x);
        s1_ = (a0_.y + a1_.y) + (a2_.y + a3_.y);
        s2_ = (a0_.z + a1_.z) + (a2_.z + a3_.z);
        s3_ = (a0_.w + a1_.w) + (a2_.w + a3_.w);
        s4_ = (b0_.x + b1_.x) + (b2_.x + b3_.x);
        s5_ = (b0_.y + b1_.y) + (b2_.y + b3_.y);
        s6_ = (b0_.z + b1_.z) + (b2_.z + b3_.z);
        s7_ = (b0_.w + b1_.w) + (b2_.w + b3_.w);
      }
      if (mh == 0) {
        if (w == 0) {
          float* gp = P.Gp + (size_t)b * NH + lane * 8;
          union { float f[2]; unsigned long long q; } q0, q1, q2, q3;
          q0.f[0] = s0_; q0.f[1] = s1_;
          q1.f[0] = s2_; q1.f[1] = s3_;
          q2.f[0] = s4_; q2.f[1] = s5_;
          q3.f[0] = s6_; q3.f[1] = s7_;
          stu64(gp, q0.q); stu64(gp + 2, q1.q); stu64(gp + 4, q2.q); stu64(gp + 6, q3.q);
        }
        __syncthreads();   // drains wave0's stores (compiler emits vmcnt(0) before barrier)
        if (tid == 0)
          __hip_atomic_fetch_add(&P.bar[640 + b], 1u, __ATOMIC_RELAXED, __HIP_MEMORY_SCOPE_AGENT);
      } else {
        __syncthreads();
        if (tid == 0) {
          while (ldu32(&P.bar[640 + b]) < (unsigned)(t + 1)) __builtin_amdgcn_s_sleep(2);
        }
        __syncthreads();
        if (w == 0) {
          const float* gp = P.Gp + (size_t)b * NH + lane * 8;
          const float* gxp = P.gx + (size_t)b * NH + lane * 8;
          union { unsigned long long q; float f[2]; } r0, r1, r2, r3, x0, x1, x2, x3;
          r0.q = ldu64(gp);     r1.q = ldu64(gp + 2);
          r2.q = ldu64(gp + 4); r3.q = ldu64(gp + 6);
          x0.q = ldu64(gxp);     x1.q = ldu64(gxp + 2);
          x2.q = ldu64(gxp + 4); x3.q = ldu64(gxp + 6);
          float v0 = fmaxf(x0.f[0] + r0.f[0] + s0_, 0.f);
          float v1 = fmaxf(x0.f[1] + r0.f[1] + s1_, 0.f);
          float v2 = fmaxf(x1.f[0] + r1.f[0] + s2_, 0.f);
          float v3 = fmaxf(x1.f[1] + r1.f[1] + s3_, 0.f);
          float v4 = fmaxf(x2.f[0] + r2.f[0] + s4_, 0.f);
          float v5 = fmaxf(x2.f[1] + r2.f[1] + s5_, 0.f);
          float v6 = fmaxf(x3.f[0] + r3.f[0] + s6_, 0.f);
          float v7 = fmaxf(x3.f[1] + r3.f[1] + s7_, 0.f);
          unsigned long long o0 =
              (unsigned long long)((unsigned)f2bf(v0) | ((unsigned)f2bf(v1) << 16)) |
              ((unsigned long long)((unsigned)f2bf(v2) | ((unsigned)f2bf(v3) << 16)) << 32);
          unsigned long long o1 =
              (unsigned long long)((unsigned)f2bf(v4) | ((unsigned)f2bf(v5) << 16)) |
              ((unsigned long long)((unsigned)f2bf(v6) | ((unsigned)f2bf(v7) << 16)) << 32);
          stu64(P.Gbf + (size_t)b * NH + lane * 8, o0);
          stu64(P.Gbf + (size_t)b * NH + lane * 8 + 4, o1);
        }
      }
    }
    gbar(P.bar, 3 * t + 2);

    // ========== P3: GRU gates -> h' ==========
    if (bid < 128) {
      int rt = bid >> 4, ct = bid & 15;
      int row0 = rt * 32 + (w & 1) * 16;
      int j0 = ct * 32 + (w >> 1) * 16;
      const unsigned short* Ag = P.Gbf + (size_t)(row0 + al) * NH;
      const unsigned short* Br = P.Wih + (size_t)(j0 + al) * 512;
      const unsigned short* Bz = P.Wih + (size_t)(j0 + 512 + al) * 512;
      const unsigned short* Bn = P.Wih + (size_t)(j0 + 1024 + al) * 512;
      f32x4 ar = {0.f, 0.f, 0.f, 0.f}, az = {0.f, 0.f, 0.f, 0.f}, an = {0.f, 0.f, 0.f, 0.f};
      bf16x8 frA[16];
#pragma unroll
      for (int i = 0; i < 16; ++i) frA[i] = ld_frag(Ag + i * 32 + kg * 8);
      int j = j0 + al;
      float ghv[4][3];
#pragma unroll
      for (int r = 0; r < 4; ++r) {
        const float* ghrow = P.gh + (size_t)(row0 + kg * 4 + r) * NG + j;
        ghv[r][0] = ldf(ghrow);
        ghv[r][1] = ldf(ghrow + 512);
        ghv[r][2] = ldf(ghrow + 1024);
      }
#pragma unroll
      for (int i = 0; i < 16; ++i) {
        ar = MFMA(frA[i], *(const bf16x8*)(Br + i * 32 + kg * 8), ar);
        az = MFMA(frA[i], *(const bf16x8*)(Bz + i * 32 + kg * 8), az);
        an = MFMA(frA[i], *(const bf16x8*)(Bn + i * 32 + kg * 8), an);
      }
      float bir = P.b_ih[j], biz = P.b_ih[j + 512], bin_ = P.b_ih[j + 1024];
#pragma unroll
      for (int r = 0; r < 4; ++r) {
        int row = row0 + kg * 4 + r;
        float rg = sigm(ar[r] + bir + ghv[r][0]);
        float zg = sigm(az[r] + biz + ghv[r][1]);
        float ng = tanhf(an[r] + bin_ + rg * ghv[r][2]);
        float hn = (1.f - zg) * ng + zg * hreg[r];
        hreg[r] = hn;
        unsigned hv = f2bf(hn);
        unsigned ov = __shfl_xor((int)hv, 1);
        if ((al & 1) == 0)
          stu32(&P.Hbf[(size_t)row * NH + (j & ~1)], hv | (ov << 16));
      }
    }
    gbar(P.bar, 3 * t + 3);
  }

  // ========== P5: out = h_T @ Wout^T + b_out ==========
  if (bid < 128) {
    int rt = bid >> 4, ct = bid & 15;
    int row0 = rt * 32 + (w & 1) * 16;
    int col0 = ct * 32 + (w >> 1) * 16;
    const unsigned short* Ah = P.Hbf + (size_t)(row0 + al) * NH;
    const unsigned short* B0 = P.Wout + (size_t)(col0 + al) * 512;
    f32x4 acc = {0.f, 0.f, 0.f, 0.f};
    bf16x8 frA[16];
#pragma unroll
    for (int i = 0; i < 16; ++i) frA[i] = ld_frag(Ah + i * 32 + kg * 8);
#pragma unroll
    for (int i = 0; i < 16; ++i) acc = MFMA(frA[i], *(const bf16x8*)(B0 + i * 32 + kg * 8), acc);
#pragma unroll
    for (int r = 0; r < 4; ++r) {
      int row = row0 + kg * 4 + r;
      P.out[row * 512 + col0 + al] = acc[r] + P.b_out[col0 + al];
    }
  }
}

extern "C" void kernel_launch(void* const* d_in, const int* in_sizes, int n_in,
                              void* d_out, int out_size, void* d_ws, size_t ws_size,
                              hipStream_t stream) {
  const float* x      = (const float*)d_in[0];
  const float* W_attn = (const float*)d_in[1];
  const float* b_attn = (const float*)d_in[2];
  const float* W_comb = (const float*)d_in[3];
  const float* b_comb = (const float*)d_in[4];
  const float* W_ih   = (const float*)d_in[5];
  const float* W_hh   = (const float*)d_in[6];
  const float* b_ih   = (const float*)d_in[7];
  const float* b_hh   = (const float*)d_in[8];
  const float* W_out  = (const float*)d_in[9];
  const float* b_out  = (const float*)d_in[10];

  char* wp = (char*)d_ws;
  size_t off = 0;
  unsigned short* XZ   = (unsigned short*)(wp + off); off += (size_t)NB * NI * NH * 2;   // 128MB (Xc then Zt)
  unsigned short* Wa   = (unsigned short*)(wp + off); off += (size_t)NI * 1024 * 2;
  unsigned short* Whh  = (unsigned short*)(wp + off); off += (size_t)NG * 512 * 2;
  unsigned short* Wc   = (unsigned short*)(wp + off); off += (size_t)NH * 1024 * 2;
  unsigned short* Wih  = (unsigned short*)(wp + off); off += (size_t)NG * 512 * 2;
  unsigned short* Wout = (unsigned short*)(wp + off); off += (size_t)512 * 512 * 2;
  unsigned short* Xt   = (unsigned short*)(wp + off); off += (size_t)2 * NB * NI * 2;
  unsigned short* Hbf  = (unsigned short*)(wp + off); off += (size_t)NB * NH * 2;
  unsigned short* Gbf  = (unsigned short*)(wp + off); off += (size_t)NB * NH * 2;
  float* logits        = (float*)(wp + off); off += (size_t)NB * NI * 4;
  float* gh            = (float*)(wp + off); off += (size_t)NB * NG * 4;
  float* gx            = (float*)(wp + off); off += (size_t)NB * NH * 4;
  float* Gp            = (float*)(wp + off); off += (size_t)NB * NH * 4;
  unsigned* bar        = (unsigned*)(wp + off); off += 4096;

  cast_f32_bf16<<<8192, 256, 0, stream>>>(x, XZ, NB * NI * NT);
  cast_f32_bf16<<<512, 256, 0, stream>>>(W_attn, Wa, NI * 1024);
  cast_f32_bf16<<<512, 256, 0, stream>>>(W_hh, Whh, NG * 512);
  cast_f32_bf16<<<512, 256, 0, stream>>>(W_comb, Wc, NH * 1024);
  cast_f32_bf16<<<512, 256, 0, stream>>>(W_ih, Wih, NG * 512);
  cast_f32_bf16<<<512, 256, 0, stream>>>(W_out, Wout, 512 * 512);
  zt_inplace<<<4096, 256, 0, stream>>>(XZ, Wc);
  init_kernel<<<512, 256, 0, stream>>>(x, Xt, Hbf, bar);

  KParams prm;
  prm.XZ = XZ; prm.Wa = Wa; prm.Whh = Whh; prm.Wc = Wc; prm.Wih = Wih; prm.Wout = Wout;
  prm.Xt = Xt; prm.Hbf = Hbf; prm.Gbf = Gbf;
  prm.logits = logits; prm.gh = gh; prm.gx = gx; prm.Gp = Gp;
  prm.x = x; prm.b_attn = b_attn; prm.b_hh = b_hh; prm.b_ih = b_ih; prm.b_out = b_out;
  prm.b_comb = b_comb;
  prm.out = (float*)d_out;
  prm.bar = bar;

  void* kargs[] = { &prm };
  hipError_t e = hipLaunchCooperativeKernel((const void*)persistent_kernel,
                                            dim3(NBLK), dim3(256), kargs, 0, stream);
  if (e != hipSuccess) {
    persistent_kernel<<<dim3(NBLK), dim3(256), 0, stream>>>(prm);
  }
}

// Round 6
// 37522.726 us; speedup vs baseline: 6.4086x; 1.0403x over previous
//
#include <hip/hip_runtime.h>

#define NB 256    // batch
#define NT 512    // T == MAXLEN
#define NI 512    // INPUTS == M
#define NH 512    // HIDDEN
#define NG 1536   // 3*H
#define NBLK 512  // persistent grid

typedef __attribute__((ext_vector_type(8))) short bf16x8;
typedef __attribute__((ext_vector_type(4))) float f32x4;

#define MFMA(a, b, c) __builtin_amdgcn_mfma_f32_16x16x32_bf16((a), (b), (c), 0, 0, 0)

// barrier/flag word offsets inside bar[] (each flag on its own 256B line)
#define BAR_LEAF(g)   ((g) * 64)           // g<16, +32/step each
#define BAR_ROOT      1024                 // +16/step
#define BAR_GEN       1088                 // +1/step
#define FLG_LOGIT(rt) (1152 + (rt) * 64)   // rt<8,  target 16*(t+1)
#define FLG_GH(rt)    (1664 + (rt) * 64)   // rt<4,  target 48*(t+1)
#define FLG_GX(rt)    (1920 + (rt) * 64)   // rt<4,  target 16*(t+1)
#define FLG_G(rg)     (2176 + (rg) * 64)   // rg<8,  target 32*(t+1)
#define FLG_GP(b)     (2688 + (b) * 64)    // b<256, target (t+1)
#define BAR_WORDS     20480

__device__ __forceinline__ unsigned short f2bf(float f) {
  unsigned int u = __float_as_uint(f);
  u = u + 0x7FFFu + ((u >> 16) & 1u);
  return (unsigned short)(u >> 16);
}
__device__ __forceinline__ float bflo(unsigned int p) { return __uint_as_float(p << 16); }
__device__ __forceinline__ float bfhi(unsigned int p) { return __uint_as_float(p & 0xffff0000u); }
__device__ __forceinline__ float sigm(float x) { return 1.f / (1.f + __expf(-x)); }

// ---- sc1 (agent-coherent, LLC) stores via relaxed atomics ----
__device__ __forceinline__ void stf(float* p, float v) {
  __hip_atomic_store(p, v, __ATOMIC_RELAXED, __HIP_MEMORY_SCOPE_AGENT);
}
__device__ __forceinline__ void stu32(void* p, unsigned v) {
  __hip_atomic_store((unsigned*)p, v, __ATOMIC_RELAXED, __HIP_MEMORY_SCOPE_AGENT);
}
__device__ __forceinline__ void stu64(void* p, unsigned long long v) {
  __hip_atomic_store((unsigned long long*)p, v, __ATOMIC_RELAXED, __HIP_MEMORY_SCOPE_AGENT);
}
// ---- sc1 pipelined LOADS via inline asm (batched; one waitcnt per burst) ----
__device__ __forceinline__ void ldg16(uint4& d, const void* p) {
  asm volatile("global_load_dwordx4 %0, %1, off sc1" : "=v"(d) : "v"(p));
}
__device__ __forceinline__ void ldg8(float2& d, const void* p) {
  asm volatile("global_load_dwordx2 %0, %1, off sc1" : "=v"(d) : "v"(p));
}
__device__ __forceinline__ void ldg4(float& d, const void* p) {
  asm volatile("global_load_dword %0, %1, off sc1" : "=v"(d) : "v"(p));
}
__device__ __forceinline__ void wait_vm0() {
  asm volatile("s_waitcnt vmcnt(0)" ::: "memory");
  __builtin_amdgcn_sched_barrier(0);   // rule #18: keep uses after the wait
}
__device__ __forceinline__ bf16x8 as_frag(uint4 v) {
  union { uint4 u; bf16x8 f; } c; c.u = v; return c.f;
}

// ---- monotonic relaxed flags ----
__device__ __forceinline__ void flag_add(unsigned* f) {
  __hip_atomic_fetch_add(f, 1u, __ATOMIC_RELAXED, __HIP_MEMORY_SCOPE_AGENT);
}
__device__ __forceinline__ void flag_wait(unsigned* f, unsigned target) {
  while (__hip_atomic_load(f, __ATOMIC_RELAXED, __HIP_MEMORY_SCOPE_AGENT) < target)
    __builtin_amdgcn_s_sleep(1);
}

// ---------------- generic f32 -> bf16 cast ----------------
__global__ __launch_bounds__(256) void cast_f32_bf16(const float* __restrict__ s,
                                                     unsigned short* __restrict__ d, int n) {
  int i = blockIdx.x * 256 + threadIdx.x;
  int stride = gridDim.x * 256;
  for (; i < n; i += stride) d[i] = f2bf(s[i]);
}

// ---------------- Zt = (bf16 X) @ Wc2^T, in place over Xc ----------------
__global__ __launch_bounds__(256) void zt_inplace(unsigned short* __restrict__ XZ,
                                                  const unsigned short* __restrict__ Wc) {
  __shared__ unsigned short As[32][552];
  const int tid = threadIdx.x;
  const int row0 = blockIdx.x * 32;
  const uint4* src = (const uint4*)(XZ + (size_t)row0 * 512);
#pragma unroll
  for (int it = 0; it < 8; ++it) {
    int e8 = tid + it * 256;
    uint4 v = src[e8];
    *(uint4*)&As[e8 >> 6][(e8 & 63) * 8] = v;
  }
  __syncthreads();
  const int lane = tid & 63, w = tid >> 6;
  const int al = lane & 15, kg = lane >> 4;
  const int rbase = (w & 1) * 16;
  const int cbase = (w >> 1) * 256;
  for (int cc = 0; cc < 16; ++cc) {
    int col0 = cbase + cc * 16;
    f32x4 acc = {0.f, 0.f, 0.f, 0.f};
    const unsigned short* Bp = Wc + (size_t)(col0 + al) * 1024 + 512;
    for (int k = 0; k < 512; k += 32) {
      bf16x8 av = *(const bf16x8*)&As[rbase + al][k + kg * 8];
      bf16x8 bv = *(const bf16x8*)(Bp + k + kg * 8);
      acc = MFMA(av, bv, acc);
    }
#pragma unroll
    for (int r = 0; r < 4; ++r) {
      int row = row0 + rbase + kg * 4 + r;
      XZ[(size_t)row * 512 + col0 + al] = f2bf(acc[r]);
    }
  }
}

// ---------------- init ----------------
__global__ __launch_bounds__(256) void init_kernel(const float* __restrict__ x,
                                                   unsigned short* __restrict__ Xt,
                                                   unsigned short* __restrict__ Hbf,
                                                   unsigned* __restrict__ bar) {
  int idx = blockIdx.x * 256 + threadIdx.x;
  if (idx < BAR_WORDS) bar[idx] = 0u;
  if (idx < NB * NI) {
    int b = idx >> 9, i = idx & 511;
    Xt[idx] = f2bf(x[((size_t)b * 512 + i) * 512]);
    Hbf[idx] = 0;
  }
}

struct KParams {
  const unsigned short* XZ;   // Zt [b][m][h] bf16
  const unsigned short* Wa;   // [512][1024]
  const unsigned short* Whh;  // [1536][512]
  const unsigned short* Wc;   // [512][1024]
  const unsigned short* Wih;  // [1536][512]
  const unsigned short* Wout; // [512][512]
  unsigned short* Xt;         // [2][256][512] bf16 (cc)
  unsigned short* Hbf;        // [256][512] bf16 h (cc)
  unsigned short* Gbf;        // [256][512] bf16 g (cc)
  float* logits;              // [256][512] (cc)
  float* gh;                  // [256][1536] (cc)
  float* gx;                  // [256][512] (cc)
  float* Gp;                  // [256][512] f32 partial ctx (cc)
  const float* x;
  const float* b_attn;
  const float* b_hh;
  const float* b_ih;
  const float* b_comb;
  const float* b_out;
  float* out;
  unsigned* bar;
};

// single per-step global barrier: 16 leaves x 32 blocks -> root(16) -> gen
__device__ __forceinline__ void gbar(unsigned* bar, unsigned gen_expect) {
  asm volatile("s_waitcnt vmcnt(0)" ::: "memory");
  __syncthreads();
  if (threadIdx.x == 0) {
    unsigned old = __hip_atomic_fetch_add(&bar[BAR_LEAF(blockIdx.x >> 5)], 1u,
                                          __ATOMIC_RELAXED, __HIP_MEMORY_SCOPE_AGENT);
    if ((old & 31) == 31) {
      unsigned ro = __hip_atomic_fetch_add(&bar[BAR_ROOT], 1u,
                                           __ATOMIC_RELAXED, __HIP_MEMORY_SCOPE_AGENT);
      if ((ro & 15) == 15)
        __hip_atomic_fetch_add(&bar[BAR_GEN], 1u,
                               __ATOMIC_RELAXED, __HIP_MEMORY_SCOPE_AGENT);
    }
    while (__hip_atomic_load(&bar[BAR_GEN], __ATOMIC_RELAXED, __HIP_MEMORY_SCOPE_AGENT) < gen_expect)
      __builtin_amdgcn_s_sleep(2);
    asm volatile("" ::: "memory");
  }
  __syncthreads();
}

__global__ __launch_bounds__(256, 2) void persistent_kernel(KParams P) {
  __shared__ float aw[512];
  __shared__ float4 pA[4][64];
  __shared__ float4 pB[4][64];
  __shared__ float red[8];
  const int bid = blockIdx.x, tid = threadIdx.x;
  const int lane = tid & 63, w = tid >> 6;
  const int al = lane & 15, kg = lane >> 4;

  f32x4 hreg = {0.f, 0.f, 0.f, 0.f};   // GRU h carry (blocks 384..511)

  for (int t = 0; t < NT; ++t) {
    const int p = t & 1, np = p ^ 1;
    // ========== P1: logits[0,128) | gh[128,320) | gx[320,384) | gather[384,512) ==========
    if (bid < 128) {
      // logits = [xt|h] @ Wa^T + b_attn : 32r x 32c tile, K=1024 (split accs)
      int rt = bid >> 4, ct = bid & 15;
      int row0 = rt * 32 + (w & 1) * 16, col0 = ct * 32 + (w >> 1) * 16;
      const unsigned short* Ax = P.Xt + (size_t)p * (NB * NI) + (size_t)(row0 + al) * NI;
      const unsigned short* Ah = P.Hbf + (size_t)(row0 + al) * NH;
      const unsigned short* B = P.Wa + (size_t)(col0 + al) * 1024;
      uint4 fx[16], fh[16];
#pragma unroll
      for (int i = 0; i < 16; ++i) ldg16(fx[i], Ax + i * 32 + kg * 8);
#pragma unroll
      for (int i = 0; i < 16; ++i) ldg16(fh[i], Ah + i * 32 + kg * 8);
      wait_vm0();
      f32x4 a0 = {0.f, 0.f, 0.f, 0.f}, a1 = {0.f, 0.f, 0.f, 0.f};
#pragma unroll
      for (int i = 0; i < 16; ++i) {
        a0 = MFMA(as_frag(fx[i]), *(const bf16x8*)(B + i * 32 + kg * 8), a0);
        a1 = MFMA(as_frag(fh[i]), *(const bf16x8*)(B + 512 + i * 32 + kg * 8), a1);
      }
#pragma unroll
      for (int r = 0; r < 4; ++r) {
        int row = row0 + kg * 4 + r;
        stf(&P.logits[row * NI + col0 + al], a0[r] + a1[r] + P.b_attn[col0 + al]);
      }
      __syncthreads();
      if (tid == 0) flag_add(&P.bar[FLG_LOGIT(rt)]);
    } else if (bid < 320) {
      // gh = h @ Whh^T + b_hh : 64r x 32c
      int b2 = bid - 128;
      int rt = b2 / 48, ct = b2 % 48;
      int row0 = rt * 64 + w * 16, col0 = ct * 32;
      const unsigned short* Ah = P.Hbf + (size_t)(row0 + al) * NH;
      const unsigned short* B0 = P.Whh + (size_t)(col0 + al) * 512;
      const unsigned short* B1 = P.Whh + (size_t)(col0 + 16 + al) * 512;
      uint4 fa[16];
#pragma unroll
      for (int i = 0; i < 16; ++i) ldg16(fa[i], Ah + i * 32 + kg * 8);
      wait_vm0();
      f32x4 a0 = {0.f, 0.f, 0.f, 0.f}, a1 = {0.f, 0.f, 0.f, 0.f};
#pragma unroll
      for (int i = 0; i < 16; ++i) {
        a0 = MFMA(as_frag(fa[i]), *(const bf16x8*)(B0 + i * 32 + kg * 8), a0);
        a1 = MFMA(as_frag(fa[i]), *(const bf16x8*)(B1 + i * 32 + kg * 8), a1);
      }
#pragma unroll
      for (int r = 0; r < 4; ++r) {
        int row = row0 + kg * 4 + r;
        stf(&P.gh[row * NG + col0 + al], a0[r] + P.b_hh[col0 + al]);
        stf(&P.gh[row * NG + col0 + 16 + al], a1[r] + P.b_hh[col0 + 16 + al]);
      }
      __syncthreads();
      if (tid == 0) flag_add(&P.bar[FLG_GH(rt)]);
    } else if (bid < 384) {
      // gx = xt @ Wc1^T + b_comb : 64r x 32c
      int b3 = bid - 320;
      int rt = b3 >> 4, ct = b3 & 15;
      int row0 = rt * 64 + w * 16, col0 = ct * 32;
      const unsigned short* Ax = P.Xt + (size_t)p * (NB * NI) + (size_t)(row0 + al) * NI;
      const unsigned short* B0 = P.Wc + (size_t)(col0 + al) * 1024;
      const unsigned short* B1 = P.Wc + (size_t)(col0 + 16 + al) * 1024;
      uint4 fa[16];
#pragma unroll
      for (int i = 0; i < 16; ++i) ldg16(fa[i], Ax + i * 32 + kg * 8);
      wait_vm0();
      f32x4 a0 = {0.f, 0.f, 0.f, 0.f}, a1 = {0.f, 0.f, 0.f, 0.f};
#pragma unroll
      for (int i = 0; i < 16; ++i) {
        a0 = MFMA(as_frag(fa[i]), *(const bf16x8*)(B0 + i * 32 + kg * 8), a0);
        a1 = MFMA(as_frag(fa[i]), *(const bf16x8*)(B1 + i * 32 + kg * 8), a1);
      }
#pragma unroll
      for (int r = 0; r < 4; ++r) {
        int row = row0 + kg * 4 + r;
        stf(&P.gx[row * NH + col0 + al], a0[r] + P.b_comb[col0 + al]);
        stf(&P.gx[row * NH + col0 + 16 + al], a1[r] + P.b_comb[col0 + 16 + al]);
      }
      __syncthreads();
      if (tid == 0) flag_add(&P.bar[FLG_GX(rt)]);
    } else {
      // gather x_{t+1} into Xt[np]
      if (t < NT - 1) {
        for (int e2 = (bid - 384) * 256 + tid; e2 < NB * NI / 2; e2 += 128 * 256) {
          int b = e2 >> 8, i = (e2 & 255) * 2;
          const float* xp = P.x + ((size_t)b * 512 + i) * 512 + t + 1;
          unsigned lo = f2bf(xp[0]);
          unsigned hi = f2bf(xp[512]);
          stu32(&P.Xt[(size_t)np * (NB * NI) + b * 512 + i], lo | (hi << 16));
        }
      }
    }

    // ========== P2: softmax + Zt-stream (block = (b, m-half)), flag-gated ==========
    {
      const int b = bid >> 1, mh = bid & 1;
      if (tid == 0) flag_wait(&P.bar[FLG_LOGIT(b >> 5)], 16u * (t + 1));
      __syncthreads();
      float2 lv;
      ldg8(lv, P.logits + (size_t)b * NI + 2 * tid);
      wait_vm0();
      float mx = fmaxf(lv.x, lv.y);
#pragma unroll
      for (int off = 32; off >= 1; off >>= 1) mx = fmaxf(mx, __shfl_xor(mx, off));
      if (lane == 0) red[w] = mx;
      __syncthreads();
      mx = fmaxf(fmaxf(red[0], red[1]), fmaxf(red[2], red[3]));
      float e0 = __expf(lv.x - mx), e1 = __expf(lv.y - mx);
      float sm = e0 + e1;
#pragma unroll
      for (int off = 32; off >= 1; off >>= 1) sm += __shfl_xor(sm, off);
      if (lane == 0) red[4 + w] = sm;
      __syncthreads();
      sm = (red[4] + red[5]) + (red[6] + red[7]);
      float inv = 1.f / sm;
      aw[2 * tid] = e0 * inv;
      aw[2 * tid + 1] = e1 * inv;
      __syncthreads();

      // wave w streams rows m = mh*256 + w*64 + [0,64) ; plain loads (L2-cacheable)
      const uint4* Z4 = (const uint4*)P.XZ + (((size_t)b * 512 + mh * 256 + w * 64) << 6) + lane;
      const float* awp = aw + mh * 256 + w * 64;
      float c0 = 0.f, c1 = 0.f, c2 = 0.f, c3 = 0.f, c4 = 0.f, c5 = 0.f, c6 = 0.f, c7 = 0.f;
#pragma unroll
      for (int mm = 0; mm < 64; mm += 16) {
        uint4 px[16];
#pragma unroll
        for (int u = 0; u < 16; ++u) px[u] = Z4[(mm + u) << 6];
#pragma unroll
        for (int u = 0; u < 16; ++u) {
          float a_ = awp[mm + u];
          c0 = fmaf(a_, bflo(px[u].x), c0); c1 = fmaf(a_, bfhi(px[u].x), c1);
          c2 = fmaf(a_, bflo(px[u].y), c2); c3 = fmaf(a_, bfhi(px[u].y), c3);
          c4 = fmaf(a_, bflo(px[u].z), c4); c5 = fmaf(a_, bfhi(px[u].z), c5);
          c6 = fmaf(a_, bflo(px[u].w), c6); c7 = fmaf(a_, bfhi(px[u].w), c7);
        }
      }
      pA[w][lane] = make_float4(c0, c1, c2, c3);
      pB[w][lane] = make_float4(c4, c5, c6, c7);
      __syncthreads();
      float s0_, s1_, s2_, s3_, s4_, s5_, s6_, s7_;
      if (w == 0) {
        float4 a0_ = pA[0][lane], a1_ = pA[1][lane], a2_ = pA[2][lane], a3_ = pA[3][lane];
        float4 b0_ = pB[0][lane], b1_ = pB[1][lane], b2_ = pB[2][lane], b3_ = pB[3][lane];
        s0_ = (a0_.x + a1_.x) + (a2_.x + a3_.x);
        s1_ = (a0_.y + a1_.y) + (a2_.y + a3_.y);
        s2_ = (a0_.z + a1_.z) + (a2_.z + a3_.z);
        s3_ = (a0_.w + a1_.w) + (a2_.w + a3_.w);
        s4_ = (b0_.x + b1_.x) + (b2_.x + b3_.x);
        s5_ = (b0_.y + b1_.y) + (b2_.y + b3_.y);
        s6_ = (b0_.z + b1_.z) + (b2_.z + b3_.z);
        s7_ = (b0_.w + b1_.w) + (b2_.w + b3_.w);
      }
      if (mh == 0) {
        if (w == 0) {
          float* gp = P.Gp + (size_t)b * NH + lane * 8;
          union { float f[2]; unsigned long long q; } q0, q1, q2, q3;
          q0.f[0] = s0_; q0.f[1] = s1_;
          q1.f[0] = s2_; q1.f[1] = s3_;
          q2.f[0] = s4_; q2.f[1] = s5_;
          q3.f[0] = s6_; q3.f[1] = s7_;
          stu64(gp, q0.q); stu64(gp + 2, q1.q); stu64(gp + 4, q2.q); stu64(gp + 6, q3.q);
        }
        __syncthreads();
        if (tid == 0) flag_add(&P.bar[FLG_GP(b)]);
      } else {
        __syncthreads();
        if (tid == 0) {
          flag_wait(&P.bar[FLG_GP(b)], (unsigned)(t + 1));
          flag_wait(&P.bar[FLG_GX(b >> 6)], 16u * (t + 1));
        }
        __syncthreads();
        if (w == 0) {
          const float* gp = P.Gp + (size_t)b * NH + lane * 8;
          const float* gxp = P.gx + (size_t)b * NH + lane * 8;
          float2 r0, r1, r2, r3, x0, x1, x2, x3;
          ldg8(r0, gp);     ldg8(r1, gp + 2);
          ldg8(r2, gp + 4); ldg8(r3, gp + 6);
          ldg8(x0, gxp);     ldg8(x1, gxp + 2);
          ldg8(x2, gxp + 4); ldg8(x3, gxp + 6);
          wait_vm0();
          float v0 = fmaxf(x0.x + r0.x + s0_, 0.f);
          float v1 = fmaxf(x0.y + r0.y + s1_, 0.f);
          float v2 = fmaxf(x1.x + r1.x + s2_, 0.f);
          float v3 = fmaxf(x1.y + r1.y + s3_, 0.f);
          float v4 = fmaxf(x2.x + r2.x + s4_, 0.f);
          float v5 = fmaxf(x2.y + r2.y + s5_, 0.f);
          float v6 = fmaxf(x3.x + r3.x + s6_, 0.f);
          float v7 = fmaxf(x3.y + r3.y + s7_, 0.f);
          unsigned long long o0 =
              (unsigned long long)((unsigned)f2bf(v0) | ((unsigned)f2bf(v1) << 16)) |
              ((unsigned long long)((unsigned)f2bf(v2) | ((unsigned)f2bf(v3) << 16)) << 32);
          unsigned long long o1 =
              (unsigned long long)((unsigned)f2bf(v4) | ((unsigned)f2bf(v5) << 16)) |
              ((unsigned long long)((unsigned)f2bf(v6) | ((unsigned)f2bf(v7) << 16)) << 32);
          stu64(P.Gbf + (size_t)b * NH + lane * 8, o0);
          stu64(P.Gbf + (size_t)b * NH + lane * 8 + 4, o1);
        }
        __syncthreads();
        if (tid == 0) flag_add(&P.bar[FLG_G(b >> 5)]);
      }
    }

    // ========== P3: GRU gates -> h' (blocks 384..511), flag-gated ==========
    if (bid >= 384) {
      int q = bid - 384;
      int rt = q >> 4, ct = q & 15;
      int row0 = rt * 32 + (w & 1) * 16;
      int j0 = ct * 32 + (w >> 1) * 16;
      if (tid == 0) {
        flag_wait(&P.bar[FLG_G(rt)], 32u * (t + 1));
        flag_wait(&P.bar[FLG_GH(rt >> 1)], 48u * (t + 1));
      }
      __syncthreads();
      const unsigned short* Ag = P.Gbf + (size_t)(row0 + al) * NH;
      const unsigned short* Br = P.Wih + (size_t)(j0 + al) * 512;
      const unsigned short* Bz = P.Wih + (size_t)(j0 + 512 + al) * 512;
      const unsigned short* Bn = P.Wih + (size_t)(j0 + 1024 + al) * 512;
      int j = j0 + al;
      uint4 fa[16];
      float ghv[4][3];
#pragma unroll
      for (int i = 0; i < 16; ++i) ldg16(fa[i], Ag + i * 32 + kg * 8);
#pragma unroll
      for (int r = 0; r < 4; ++r) {
        const float* ghrow = P.gh + (size_t)(row0 + kg * 4 + r) * NG + j;
        ldg4(ghv[r][0], ghrow);
        ldg4(ghv[r][1], ghrow + 512);
        ldg4(ghv[r][2], ghrow + 1024);
      }
      wait_vm0();
      f32x4 ar = {0.f, 0.f, 0.f, 0.f}, az = {0.f, 0.f, 0.f, 0.f}, an = {0.f, 0.f, 0.f, 0.f};
#pragma unroll
      for (int i = 0; i < 16; ++i) {
        ar = MFMA(as_frag(fa[i]), *(const bf16x8*)(Br + i * 32 + kg * 8), ar);
        az = MFMA(as_frag(fa[i]), *(const bf16x8*)(Bz + i * 32 + kg * 8), az);
        an = MFMA(as_frag(fa[i]), *(const bf16x8*)(Bn + i * 32 + kg * 8), an);
      }
      float bir = P.b_ih[j], biz = P.b_ih[j + 512], bin_ = P.b_ih[j + 1024];
#pragma unroll
      for (int r = 0; r < 4; ++r) {
        int row = row0 + kg * 4 + r;
        float rg = sigm(ar[r] + bir + ghv[r][0]);
        float zg = sigm(az[r] + biz + ghv[r][1]);
        float ng = tanhf(an[r] + bin_ + rg * ghv[r][2]);
        float hn = (1.f - zg) * ng + zg * hreg[r];
        hreg[r] = hn;
        unsigned hv = f2bf(hn);
        unsigned ov = __shfl_xor((int)hv, 1);
        if ((al & 1) == 0)
          stu32(&P.Hbf[(size_t)row * NH + (j & ~1)], hv | (ov << 16));
      }
    }
    gbar(P.bar, (unsigned)(t + 1));
  }

  // ========== epilogue: out = h_T @ Wout^T + b_out ==========
  if (bid < 128) {
    int rt = bid >> 4, ct = bid & 15;
    int row0 = rt * 32 + (w & 1) * 16;
    int col0 = ct * 32 + (w >> 1) * 16;
    const unsigned short* Ah = P.Hbf + (size_t)(row0 + al) * NH;
    const unsigned short* B0 = P.Wout + (size_t)(col0 + al) * 512;
    uint4 fa[16];
#pragma unroll
    for (int i = 0; i < 16; ++i) ldg16(fa[i], Ah + i * 32 + kg * 8);
    wait_vm0();
    f32x4 acc = {0.f, 0.f, 0.f, 0.f};
#pragma unroll
    for (int i = 0; i < 16; ++i) acc = MFMA(as_frag(fa[i]), *(const bf16x8*)(B0 + i * 32 + kg * 8), acc);
#pragma unroll
    for (int r = 0; r < 4; ++r) {
      int row = row0 + kg * 4 + r;
      P.out[row * 512 + col0 + al] = acc[r] + P.b_out[col0 + al];
    }
  }
}

extern "C" void kernel_launch(void* const* d_in, const int* in_sizes, int n_in,
                              void* d_out, int out_size, void* d_ws, size_t ws_size,
                              hipStream_t stream) {
  const float* x      = (const float*)d_in[0];
  const float* W_attn = (const float*)d_in[1];
  const float* b_attn = (const float*)d_in[2];
  const float* W_comb = (const float*)d_in[3];
  const float* b_comb = (const float*)d_in[4];
  const float* W_ih   = (const float*)d_in[5];
  const float* W_hh   = (const float*)d_in[6];
  const float* b_ih   = (const float*)d_in[7];
  const float* b_hh   = (const float*)d_in[8];
  const float* W_out  = (const float*)d_in[9];
  const float* b_out  = (const float*)d_in[10];

  char* wp = (char*)d_ws;
  size_t off = 0;
  unsigned short* XZ   = (unsigned short*)(wp + off); off += (size_t)NB * NI * NH * 2;   // 128MB
  unsigned short* Wa   = (unsigned short*)(wp + off); off += (size_t)NI * 1024 * 2;
  unsigned short* Whh  = (unsigned short*)(wp + off); off += (size_t)NG * 512 * 2;
  unsigned short* Wc   = (unsigned short*)(wp + off); off += (size_t)NH * 1024 * 2;
  unsigned short* Wih  = (unsigned short*)(wp + off); off += (size_t)NG * 512 * 2;
  unsigned short* Wout = (unsigned short*)(wp + off); off += (size_t)512 * 512 * 2;
  unsigned short* Xt   = (unsigned short*)(wp + off); off += (size_t)2 * NB * NI * 2;
  unsigned short* Hbf  = (unsigned short*)(wp + off); off += (size_t)NB * NH * 2;
  unsigned short* Gbf  = (unsigned short*)(wp + off); off += (size_t)NB * NH * 2;
  float* logits        = (float*)(wp + off); off += (size_t)NB * NI * 4;
  float* gh            = (float*)(wp + off); off += (size_t)NB * NG * 4;
  float* gx            = (float*)(wp + off); off += (size_t)NB * NH * 4;
  float* Gp            = (float*)(wp + off); off += (size_t)NB * NH * 4;
  unsigned* bar        = (unsigned*)(wp + off); off += (size_t)BAR_WORDS * 4 + 4096;

  cast_f32_bf16<<<8192, 256, 0, stream>>>(x, XZ, NB * NI * NT);
  cast_f32_bf16<<<512, 256, 0, stream>>>(W_attn, Wa, NI * 1024);
  cast_f32_bf16<<<512, 256, 0, stream>>>(W_hh, Whh, NG * 512);
  cast_f32_bf16<<<512, 256, 0, stream>>>(W_comb, Wc, NH * 1024);
  cast_f32_bf16<<<512, 256, 0, stream>>>(W_ih, Wih, NG * 512);
  cast_f32_bf16<<<512, 256, 0, stream>>>(W_out, Wout, 512 * 512);
  zt_inplace<<<4096, 256, 0, stream>>>(XZ, Wc);
  init_kernel<<<512, 256, 0, stream>>>(x, Xt, Hbf, bar);

  KParams prm;
  prm.XZ = XZ; prm.Wa = Wa; prm.Whh = Whh; prm.Wc = Wc; prm.Wih = Wih; prm.Wout = Wout;
  prm.Xt = Xt; prm.Hbf = Hbf; prm.Gbf = Gbf;
  prm.logits = logits; prm.gh = gh; prm.gx = gx; prm.Gp = Gp;
  prm.x = x; prm.b_attn = b_attn; prm.b_hh = b_hh; prm.b_ih = b_ih; prm.b_out = b_out;
  prm.b_comb = b_comb;
  prm.out = (float*)d_out;
  prm.bar = bar;

  void* kargs[] = { &prm };
  hipError_t e = hipLaunchCooperativeKernel((const void*)persistent_kernel,
                                            dim3(NBLK), dim3(256), kargs, 0, stream);
  if (e != hipSuccess) {
    persistent_kernel<<<dim3(NBLK), dim3(256), 0, stream>>>(prm);
  }
}